// Round 18
// baseline (256.438 us; speedup 1.0000x reference)
//
#include <hip/hip_runtime.h>

#define Bq 4
#define Tq 16
#define Nq 4096
#define NFq 8
#define Hq 64
#define Eq 131072
#define Cq 13
#define Mq (Bq*Nq)

typedef __attribute__((ext_vector_type(8))) short bf16x8;
typedef __attribute__((ext_vector_type(4))) float f32x4;

// ---------- helpers ----------
__device__ __forceinline__ float bf2f(unsigned short u) {
  return __uint_as_float(((unsigned int)u) << 16);
}
__device__ __forceinline__ unsigned short f2bf(float f) {
  unsigned int x = __float_as_uint(f);
  unsigned int r = x + 0x7fff + ((x >> 16) & 1);
  return (unsigned short)(r >> 16);
}
__device__ __forceinline__ float rcpf(float x) {
  float r;
  asm("v_rcp_f32 %0, %1" : "=v"(r) : "v"(x));
  return r;
}
__device__ __forceinline__ float sigf(float x) {
  return rcpf(1.f + __expf(-x));
}
__device__ __forceinline__ float tanh_c(float x) {
  float e = __expf(-2.f * x);
  return 2.f * rcpf(1.f + e) - 1.f;
}
__device__ __forceinline__ unsigned int pk_bf16(float lo, float hi) {
  unsigned int r;
  asm("v_cvt_pk_bf16_f32 %0, %1, %2" : "=v"(r) : "v"(lo), "v"(hi));
  return r;
}
__device__ __forceinline__ float dot2bf(unsigned int a, unsigned int b, float c) {
  float r;
  asm("v_dot2_f32_bf16 %0, %1, %2, %3" : "=v"(r) : "v"(a), "v"(b), "v"(c));
  return r;
}

// wT float offsets
#define O_BC0  65536
#define O_BC1  65792
#define O_QB   70144
#define O_VB   74304
#define O_B1P  95872

// WB (bf16 blob) ushort offsets (global). AQT/WVT/P1OW/P2T/P3T are k-PAIR-PACKED.
#define WB_AQT  0
#define WB_AWK  4096
#define WB_WVT  8192
#define WB_P1OW 12288
#define WB_P2T  20480
#define WB_P3T  28672
#define WB_TOT  29696

// k_attn LDS layout
#define AQT_P   0
#define WVT_P   2048
#define P1OW_P  4096
#define P2T_P   8192
#define WAVE_SCR 3648
#define SMEM_ATTN (49152 + 8 * WAVE_SCR)

// ---------- K0: LSTM bias combine ----------
__global__ __launch_bounds__(256) void k_prep(
    const float* __restrict__ bih0, const float* __restrict__ bhh0,
    const float* __restrict__ bih1, const float* __restrict__ bhh1,
    float* __restrict__ wT) {
  int i = threadIdx.x;
  wT[O_BC0 + i] = bih0[i] + bhh0[i];
  wT[O_BC1 + i] = bih1[i] + bhh1[i];
}

// ---------- K0a: pack LSTM weights into MFMA A-fragments, GATE-INTERLEAVED ----------
__global__ __launch_bounds__(256) void k_prep_wa(
    const float* __restrict__ wih0, const float* __restrict__ whh0,
    const float* __restrict__ wih1, const float* __restrict__ whh1,
    unsigned short* __restrict__ WA) {
  int i = blockIdx.x * 256 + threadIdx.x;    // 0..65535
  int j = i & 7, lane = (i >> 3) & 63, ks = (i >> 9) & 3;
  int mt = (i >> 11) & 15, L = (i >> 15) & 1;
  int rp = 16 * mt + (lane & 15);
  int orig = (rp & 3) * 64 + (rp >> 2);      // gate-major original row
  int k = 32 * ks + 8 * (lane >> 4) + j;
  const float* w = L ? (k < 64 ? wih1 : whh1) : (k < 64 ? wih0 : whh0);
  WA[i] = f2bf(w[orig * 64 + (k & 63)]);
}

// ---------- K0b: attention weight pack + encoder w2 A-frag pack ----------
__global__ __launch_bounds__(256) void k_prep2(
    const float* __restrict__ aw, const float* __restrict__ ab,
    const float* __restrict__ pw2, const float* __restrict__ pw3,
    const float* __restrict__ sw2,
    unsigned short* __restrict__ WBu, unsigned short* __restrict__ WE,
    float* __restrict__ wT) {
  int i = blockIdx.x * 256 + threadIdx.x;   // 0..8191
  if (i < 4096) {
    int k = i >> 6, ch = i & 63;
    int pidx = (k >> 1) * 128 + ch * 2 + (k & 1);
    WBu[WB_AQT + pidx] = f2bf(0.25f * aw[ch * 64 + k]);   // Aq^T, scale folded
    WBu[WB_AWK + i]    = f2bf(aw[(64 + k) * 64 + ch]);    // Wk rows (element order)
    WBu[WB_WVT + pidx] = f2bf(aw[(128 + ch) * 64 + k]);   // Wv^T
    int e = i & 7, l = (i >> 3) & 63, eks = (i >> 9) & 1, mt = i >> 10;
    WE[i] = f2bf(sw2[(mt * 16 + (l & 15)) * 64 + 32 * eks + 8 * (l >> 4) + e]);
  }
  {
    int k = i >> 6, j = i & 63;                            // P2T k<128
    int pidx = (k >> 1) * 128 + j * 2 + (k & 1);
    WBu[WB_P2T + pidx] = f2bf(pw2[j * 128 + k]);
  }
  if (i < 1024) {
    int k = i >> 4, c = i & 15;
    int pidx = (k >> 1) * 32 + c * 2 + (k & 1);
    WBu[WB_P3T + pidx] = (c < 13) ? f2bf(pw3[c * 64 + k]) : (unsigned short)0;
  }
  if (i < 64) {
    wT[O_QB + i] = 0.25f * ab[i];
    wT[O_VB + i] = ab[128 + i];
  }
}

// ---------- K0c: fold out-projection into pw1 (k-pair-packed) ----------
__global__ __launch_bounds__(256) void k_prep3(
    const float* __restrict__ pw1, const float* __restrict__ ow,
    const float* __restrict__ ob, const float* __restrict__ pb1,
    unsigned short* __restrict__ WBu, float* __restrict__ wT) {
  int i = blockIdx.x * 256 + threadIdx.x;  // 0..8191
  int j = i >> 6, k = i & 63;
  float s0 = 0.f, s1 = 0.f, s2 = 0.f, s3 = 0.f;
  for (int m2 = 0; m2 < 64; m2 += 4) {
    s0 += pw1[j * 64 + m2]     * ow[m2 * 64 + k];
    s1 += pw1[j * 64 + m2 + 1] * ow[(m2 + 1) * 64 + k];
    s2 += pw1[j * 64 + m2 + 2] * ow[(m2 + 2) * 64 + k];
    s3 += pw1[j * 64 + m2 + 3] * ow[(m2 + 3) * 64 + k];
  }
  WBu[WB_P1OW + (k >> 1) * 256 + j * 2 + (k & 1)] = f2bf((s0 + s1) + (s2 + s3));
  if (k == 0) {
    float b = pb1[j];
    for (int m2 = 0; m2 < 64; ++m2) b += pw1[j * 64 + m2] * ob[m2];
    wT[O_B1P + j] = b;
  }
}

// ---------- K1: spatial encoder — layer1 f32, layer2 MFMA ----------
__global__ __launch_bounds__(256) void k_enc(
    const float* __restrict__ nf, const float* __restrict__ w1,
    const float* __restrict__ b1, const unsigned short* __restrict__ WE,
    const float* __restrict__ b2, unsigned short* __restrict__ henc) {
  __shared__ float xr[64][9];
  __shared__ unsigned short H1F[4096];
  __shared__ unsigned short OUT[64 * 72];
  int tid = threadIdx.x;
  int lane = tid & 63;
  int wv = tid >> 6;
  size_t row0 = (size_t)blockIdx.x * 64;
  {
    float2 v = ((const float2*)(nf + row0 * 8))[tid];
    int r = tid >> 2, q = tid & 3;
    xr[r][q * 2] = v.x;
    xr[r][q * 2 + 1] = v.y;
  }
  bf16x8 afr0, afr1;
  {
    const bf16x8* we8 = (const bf16x8*)WE;
    afr0 = we8[(wv * 2 + 0) * 64 + lane];
    afr1 = we8[(wv * 2 + 1) * 64 + lane];
  }
  int chb = wv * 16 + (lane >> 4) * 4;
  float4 b2v;
  b2v.x = b2[chb]; b2v.y = b2[chb + 1]; b2v.z = b2[chb + 2]; b2v.w = b2[chb + 3];
  __syncthreads();
  {
    int r = lane;
    float x0 = xr[r][0], x1 = xr[r][1], x2v = xr[r][2], x3 = xr[r][3];
    float x4 = xr[r][4], x5 = xr[r][5], x6 = xr[r][6], x7 = xr[r][7];
    #pragma unroll
    for (int run = 0; run < 2; ++run) {
      unsigned int pk4[4];
      #pragma unroll
      for (int p = 0; p < 4; ++p) {
        int j0 = wv * 16 + run * 8 + p * 2;
        const float* wr0 = w1 + j0 * 8;
        const float* wr1 = wr0 + 8;
        float a0 = b1[j0]     + wr0[0]*x0 + wr0[1]*x1 + wr0[2]*x2v + wr0[3]*x3
                              + wr0[4]*x4 + wr0[5]*x5 + wr0[6]*x6 + wr0[7]*x7;
        float a1 = b1[j0 + 1] + wr1[0]*x0 + wr1[1]*x1 + wr1[2]*x2v + wr1[3]*x3
                              + wr1[4]*x4 + wr1[5]*x5 + wr1[6]*x6 + wr1[7]*x7;
        pk4[p] = pk_bf16(fmaxf(a0, 0.f), fmaxf(a1, 0.f));
      }
      int jb = wv * 16 + run * 8;
      int ks = jb >> 5;
      int l2 = (lane & 15) | (((jb >> 3) & 3) << 4);
      int nt = lane >> 4;
      uint4 v; v.x = pk4[0]; v.y = pk4[1]; v.z = pk4[2]; v.w = pk4[3];
      *(uint4*)(&H1F[((ks * 4 + nt) * 64 + l2) * 8]) = v;
    }
  }
  __syncthreads();
  {
    #pragma unroll
    for (int nt = 0; nt < 4; ++nt) {
      f32x4 acc = (f32x4){b2v.x, b2v.y, b2v.z, b2v.w};
      bf16x8 bf0 = *(const bf16x8*)(&H1F[((0 * 4 + nt) * 64 + lane) * 8]);
      bf16x8 bf1 = *(const bf16x8*)(&H1F[((1 * 4 + nt) * 64 + lane) * 8]);
      acc = __builtin_amdgcn_mfma_f32_16x16x32_bf16(afr0, bf0, acc, 0, 0, 0);
      acc = __builtin_amdgcn_mfma_f32_16x16x32_bf16(afr1, bf1, acc, 0, 0, 0);
      int orow = nt * 16 + (lane & 15);
      uint2 pv;
      pv.x = pk_bf16(acc[0], acc[1]);
      pv.y = pk_bf16(acc[2], acc[3]);
      *(uint2*)(&OUT[orow * 72 + chb]) = pv;
    }
  }
  __syncthreads();
  {
    int rr = tid >> 2, part = tid & 3;
    uint4 v0 = *(uint4*)(&OUT[rr * 72 + part * 16]);
    uint4 v1 = *(uint4*)(&OUT[rr * 72 + part * 16 + 8]);
    *(uint4*)(henc + (row0 + rr) * 64 + part * 16) = v0;
    *(uint4*)(henc + (row0 + rr) * 64 + part * 16 + 8) = v1;
  }
}

// ---------- K2: per-block LDS histogram (NO global atomics) ----------
__global__ __launch_bounds__(1024) void k_count(const int* __restrict__ ei,
                                                int* __restrict__ bhist) {
  __shared__ int hist[4096];
  int b = blockIdx.x;
  int t = b & 15, seg = b >> 4;
  int tid = threadIdx.x;
  #pragma unroll
  for (int i = tid; i < 4096; i += 1024) hist[i] = 0;
  __syncthreads();
  const int* dstp = ei + ((t << 1) + 1) * Eq + (seg << 13);
  #pragma unroll
  for (int u = 0; u < 8; ++u) {
    int dst = dstp[(u << 10) + tid];
    atomicAdd(&hist[dst], 1);
  }
  __syncthreads();
  int* op = bhist + (b << 12);
  #pragma unroll
  for (int i = tid; i < 4096; i += 1024) op[i] = hist[i];
}

// ---------- K3: scan -> rp + per-segment bases segoff[t*16+seg][node] ----------
__global__ __launch_bounds__(256) void k_scan(const int* __restrict__ bhist,
                                              int* __restrict__ rp,
                                              int* __restrict__ segoff) {
  int t = blockIdx.x, tid = threadIdx.x;
  __shared__ int part[256];
  int loc[16];
  int s = 0;
  #pragma unroll
  for (int j = 0; j < 16; ++j) {
    int node = tid * 16 + j;
    int v = 0;
    #pragma unroll
    for (int seg = 0; seg < 16; ++seg)
      v += bhist[((t + (seg << 4)) << 12) + node];
    loc[j] = v;
    s += v;
  }
  part[tid] = s;
  __syncthreads();
  if (tid == 0) {
    int run = 0;
    for (int i2 = 0; i2 < 256; ++i2) { int v = part[i2]; part[i2] = run; run += v; }
  }
  __syncthreads();
  int off = part[tid];
  #pragma unroll
  for (int j = 0; j < 16; ++j) {
    int node = tid * 16 + j;
    rp[t * (Nq + 1) + node] = off;
    int running = off;
    #pragma unroll
    for (int seg = 0; seg < 16; ++seg) {
      segoff[(((t << 4) + seg) << 12) + node] = running;
      running += bhist[((t + (seg << 4)) << 12) + node];
    }
    off += loc[j];
  }
  if (tid == 255) rp[t * (Nq + 1) + Nq] = off;
}

// ---------- K4: scatter via LDS positions (no global atomics) ----------
__global__ __launch_bounds__(1024) void k_scatter(const int* __restrict__ ei,
    const int* __restrict__ segoff, int* __restrict__ col) {
  __shared__ int loff[4096];
  int b = blockIdx.x;                      // 256
  int t = b & 15, seg = b >> 4;
  int tid = threadIdx.x;
  for (int i = tid; i < 4096; i += 1024)
    loff[i] = segoff[(((t << 4) + seg) << 12) + i];
  __syncthreads();
  const int* srcp = ei + (t << 1) * Eq + (seg << 13);
  const int* dstp = ei + ((t << 1) + 1) * Eq + (seg << 13);
  #pragma unroll
  for (int u = 0; u < 8; ++u) {
    int e = (u << 10) + tid;
    int src = srcp[e];
    int dst = dstp[e];
    int pos = atomicAdd(&loff[dst], 1);
    col[(t << 17) + pos] = src;
  }
}

// ---------- K5: message passing; dot2-ones accumulation (1 instr/channel) ----------
__global__ __launch_bounds__(256) void k_mp(const unsigned short* __restrict__ henc,
    const int* __restrict__ rp, const int* __restrict__ col,
    unsigned short* __restrict__ hmp) {
  const unsigned int ONE_LO = 0x00003F80u;   // bf16 {lo=1.0, hi=0}
  const unsigned int ONE_HI = 0x3F800000u;   // bf16 {lo=0, hi=1.0}
  int lane = threadIdx.x & 63;
  int bkk = blockIdx.x;                    // 16384
  int t = bkk & 15;
  int n = (bkk >> 4) * 4 + __builtin_amdgcn_readfirstlane(threadIdx.x >> 6);
  const int* rpt = rp + t * (Nq + 1);
  const int* colt = col + (t << 17);
  int e0 = rpt[n], e1 = rpt[n + 1];
  int half = lane >> 5;
  int b2 = (lane >> 3) & 3;
  int c8 = (lane & 7) << 3;
  const unsigned short* hb2 = henc + (size_t)b2 * 4194304 + t * 262144 + c8;
  float acc[8] = {0.f, 0.f, 0.f, 0.f, 0.f, 0.f, 0.f, 0.f};
  int e = e0;
  for (; e + 8 <= e1; e += 8) {
    int i0 = colt[e + half];
    int i1 = colt[e + 2 + half];
    int i2 = colt[e + 4 + half];
    int i3 = colt[e + 6 + half];
    uint4 p0 = *(const uint4*)(hb2 + i0 * 64);
    uint4 p1 = *(const uint4*)(hb2 + i1 * 64);
    uint4 p2 = *(const uint4*)(hb2 + i2 * 64);
    uint4 p3 = *(const uint4*)(hb2 + i3 * 64);
    acc[0] = dot2bf(p0.x, ONE_LO, acc[0]); acc[0] = dot2bf(p1.x, ONE_LO, acc[0]);
    acc[0] = dot2bf(p2.x, ONE_LO, acc[0]); acc[0] = dot2bf(p3.x, ONE_LO, acc[0]);
    acc[1] = dot2bf(p0.x, ONE_HI, acc[1]); acc[1] = dot2bf(p1.x, ONE_HI, acc[1]);
    acc[1] = dot2bf(p2.x, ONE_HI, acc[1]); acc[1] = dot2bf(p3.x, ONE_HI, acc[1]);
    acc[2] = dot2bf(p0.y, ONE_LO, acc[2]); acc[2] = dot2bf(p1.y, ONE_LO, acc[2]);
    acc[2] = dot2bf(p2.y, ONE_LO, acc[2]); acc[2] = dot2bf(p3.y, ONE_LO, acc[2]);
    acc[3] = dot2bf(p0.y, ONE_HI, acc[3]); acc[3] = dot2bf(p1.y, ONE_HI, acc[3]);
    acc[3] = dot2bf(p2.y, ONE_HI, acc[3]); acc[3] = dot2bf(p3.y, ONE_HI, acc[3]);
    acc[4] = dot2bf(p0.z, ONE_LO, acc[4]); acc[4] = dot2bf(p1.z, ONE_LO, acc[4]);
    acc[4] = dot2bf(p2.z, ONE_LO, acc[4]); acc[4] = dot2bf(p3.z, ONE_LO, acc[4]);
    acc[5] = dot2bf(p0.z, ONE_HI, acc[5]); acc[5] = dot2bf(p1.z, ONE_HI, acc[5]);
    acc[5] = dot2bf(p2.z, ONE_HI, acc[5]); acc[5] = dot2bf(p3.z, ONE_HI, acc[5]);
    acc[6] = dot2bf(p0.w, ONE_LO, acc[6]); acc[6] = dot2bf(p1.w, ONE_LO, acc[6]);
    acc[6] = dot2bf(p2.w, ONE_LO, acc[6]); acc[6] = dot2bf(p3.w, ONE_LO, acc[6]);
    acc[7] = dot2bf(p0.w, ONE_HI, acc[7]); acc[7] = dot2bf(p1.w, ONE_HI, acc[7]);
    acc[7] = dot2bf(p2.w, ONE_HI, acc[7]); acc[7] = dot2bf(p3.w, ONE_HI, acc[7]);
  }
  if (half == 0) {
    for (; e < e1; ++e) {
      int i0 = colt[e];
      uint4 p0 = *(const uint4*)(hb2 + i0 * 64);
      acc[0] = dot2bf(p0.x, ONE_LO, acc[0]);
      acc[1] = dot2bf(p0.x, ONE_HI, acc[1]);
      acc[2] = dot2bf(p0.y, ONE_LO, acc[2]);
      acc[3] = dot2bf(p0.y, ONE_HI, acc[3]);
      acc[4] = dot2bf(p0.z, ONE_LO, acc[4]);
      acc[5] = dot2bf(p0.z, ONE_HI, acc[5]);
      acc[6] = dot2bf(p0.w, ONE_LO, acc[6]);
      acc[7] = dot2bf(p0.w, ONE_HI, acc[7]);
    }
  }
  #pragma unroll
  for (int i = 0; i < 8; ++i) acc[i] += __shfl_xor(acc[i], 32);
  uint4 ps = *(const uint4*)(hb2 + n * 64);
  int deg = e1 - e0;
  if (half == 0) {
    uint4 out;
    if (deg > 0) {
      float sc = 0.5f * rcpf((float)deg);
      float s0 = bf2f((unsigned short)(ps.x & 0xffff)) * 0.5f + acc[0] * sc;
      float s1 = bf2f((unsigned short)(ps.x >> 16))    * 0.5f + acc[1] * sc;
      float s2 = bf2f((unsigned short)(ps.y & 0xffff)) * 0.5f + acc[2] * sc;
      float s3 = bf2f((unsigned short)(ps.y >> 16))    * 0.5f + acc[3] * sc;
      float s4 = bf2f((unsigned short)(ps.z & 0xffff)) * 0.5f + acc[4] * sc;
      float s5 = bf2f((unsigned short)(ps.z >> 16))    * 0.5f + acc[5] * sc;
      float s6 = bf2f((unsigned short)(ps.w & 0xffff)) * 0.5f + acc[6] * sc;
      float s7 = bf2f((unsigned short)(ps.w >> 16))    * 0.5f + acc[7] * sc;
      out.x = pk_bf16(s0, s1);
      out.y = pk_bf16(s2, s3);
      out.z = pk_bf16(s4, s5);
      out.w = pk_bf16(s6, s7);
    } else {
      out = ps;
    }
    *(uint4*)(hmp + (size_t)b2 * 4194304 + t * 262144 + n * 64 + c8) = out;
  }
}

// ---------- K6: fused 2-layer LSTM; 64 seqs/block, 2-barrier pipelined steps ----------
__global__ __launch_bounds__(1024) void k_lstm(
    const unsigned short* __restrict__ hmp,
    const unsigned short* __restrict__ WA,
    const float* __restrict__ wT,
    unsigned short* __restrict__ x2) {
  __shared__ unsigned short XF[2][4096];
  __shared__ unsigned short H0F[2][4096];
  __shared__ unsigned short H1F[2][4096];
  __shared__ unsigned short OUTB[64 * 68];
  int tid = threadIdx.x;
  int l = tid & 63;
  int w = tid >> 6;
  int mtp = w >> 1, ntp = w & 1;
  int m0 = blockIdx.x << 6;

  bf16x8 afr[2][2][4];
  const bf16x8* wa8 = (const bf16x8*)WA;
  #pragma unroll
  for (int L = 0; L < 2; ++L)
    #pragma unroll
    for (int mt2 = 0; mt2 < 2; ++mt2)
      #pragma unroll
      for (int ks = 0; ks < 4; ++ks)
        afr[L][mt2][ks] = wa8[((L * 16 + (2 * mtp + mt2)) * 4 + ks) * 64 + l];

  float4 bias0[2], bias1[2];
  int hbase[2], obase[2];
  #pragma unroll
  for (int mt2 = 0; mt2 < 2; ++mt2) {
    int ch = 4 * (2 * mtp + mt2) + (l >> 4);
    bias0[mt2].x = wT[O_BC0 + ch];       bias0[mt2].y = wT[O_BC0 + 64 + ch];
    bias0[mt2].z = wT[O_BC0 + 128 + ch]; bias0[mt2].w = wT[O_BC0 + 192 + ch];
    bias1[mt2].x = wT[O_BC1 + ch];       bias1[mt2].y = wT[O_BC1 + 64 + ch];
    bias1[mt2].z = wT[O_BC1 + 128 + ch]; bias1[mt2].w = wT[O_BC1 + 192 + ch];
    int l2 = (l & 15) | (((ch >> 3) & 3) << 4);
    hbase[mt2] = (ch >> 5) * 2048 + l2 * 8 + (ch & 7);
    obase[mt2] = (l & 15) * 68 + ch;
  }
  float c0a[2][2] = {{0.f, 0.f}, {0.f, 0.f}};
  float c1a[2][2] = {{0.f, 0.f}, {0.f, 0.f}};

  int sA = tid >> 4, c4 = (tid & 15) << 2;
  int xfidx = (((c4 >> 5) * 4 + (sA >> 4)) * 64 + ((sA & 15) | (((c4 >> 3) & 3) << 4))) * 8 + (c4 & 7);
  int mm = m0 + sA;
  int bb = mm >> 12, nn = mm & 4095;
  const unsigned short* srcb = hmp + ((size_t)(bb * 16) * 4096 + (size_t)nn) * 64 + c4;
  unsigned short* x2g = x2 + (size_t)mm * (Tq * Hq) + c4;
  int outsrc = sA * 68 + c4;

  int* hz0 = (int*)&H0F[1][0];
  int* hz1 = (int*)&H1F[1][0];
  for (int i = tid; i < 2048; i += 1024) { hz0[i] = 0; hz1[i] = 0; }

  uint2 xv = *(const uint2*)srcb;
  *(uint2*)(&XF[0][0] + xfidx) = xv;
  __syncthreads();

  for (int t = 0; t < Tq; ++t) {
    int cur = t & 1, prv = cur ^ 1;

    if (t > 0) {
      uint2 ov = *(const uint2*)(OUTB + outsrc);
      *(uint2*)(x2g + (t - 1) * 64) = ov;
    }
    if (t < Tq - 1) xv = *(const uint2*)(srcb + (t + 1) * 262144);
    {
      f32x4 acc[2][2];
      #pragma unroll
      for (int mt2 = 0; mt2 < 2; ++mt2)
        #pragma unroll
        for (int nt2 = 0; nt2 < 2; ++nt2) {
          float4 bv = bias0[mt2];
          acc[mt2][nt2] = (f32x4){bv.x, bv.y, bv.z, bv.w};
        }
      #pragma unroll
      for (int nt2 = 0; nt2 < 2; ++nt2) {
        int nt = 2 * ntp + nt2;
        #pragma unroll
        for (int ks = 0; ks < 4; ++ks) {
          const unsigned short* bs = (ks < 2) ? &XF[cur][0] : &H0F[prv][0];
          bf16x8 bf = *(const bf16x8*)(bs + (((ks & 1) * 4 + nt) * 64 + l) * 8);
          acc[0][nt2] = __builtin_amdgcn_mfma_f32_16x16x32_bf16(afr[0][0][ks], bf, acc[0][nt2], 0, 0, 0);
          acc[1][nt2] = __builtin_amdgcn_mfma_f32_16x16x32_bf16(afr[0][1][ks], bf, acc[1][nt2], 0, 0, 0);
        }
      }
      #pragma unroll
      for (int mt2 = 0; mt2 < 2; ++mt2) {
        float hh[2];
        #pragma unroll
        for (int nt2 = 0; nt2 < 2; ++nt2) {
          f32x4 g = acc[mt2][nt2];
          float ig = sigf(g[0]);
          float fg = sigf(g[1]);
          float gg = tanh_c(g[2]);
          float og = sigf(g[3]);
          float c = fg * c0a[mt2][nt2] + ig * gg;
          c0a[mt2][nt2] = c;
          hh[nt2] = og * tanh_c(c);
        }
        unsigned int pk = pk_bf16(hh[0], hh[1]);
        int base = hbase[mt2] + 2 * ntp * 512;
        H0F[cur][base]       = (unsigned short)pk;
        H0F[cur][base + 512] = (unsigned short)(pk >> 16);
      }
    }
    __syncthreads();

    {
      f32x4 acc[2][2];
      #pragma unroll
      for (int mt2 = 0; mt2 < 2; ++mt2)
        #pragma unroll
        for (int nt2 = 0; nt2 < 2; ++nt2) {
          float4 bv = bias1[mt2];
          acc[mt2][nt2] = (f32x4){bv.x, bv.y, bv.z, bv.w};
        }
      #pragma unroll
      for (int nt2 = 0; nt2 < 2; ++nt2) {
        int nt = 2 * ntp + nt2;
        #pragma unroll
        for (int ks = 0; ks < 4; ++ks) {
          const unsigned short* bs = (ks < 2) ? &H0F[cur][0] : &H1F[prv][0];
          bf16x8 bf = *(const bf16x8*)(bs + (((ks & 1) * 4 + nt) * 64 + l) * 8);
          acc[0][nt2] = __builtin_amdgcn_mfma_f32_16x16x32_bf16(afr[1][0][ks], bf, acc[0][nt2], 0, 0, 0);
          acc[1][nt2] = __builtin_amdgcn_mfma_f32_16x16x32_bf16(afr[1][1][ks], bf, acc[1][nt2], 0, 0, 0);
        }
      }
      #pragma unroll
      for (int mt2 = 0; mt2 < 2; ++mt2) {
        float hh[2];
        #pragma unroll
        for (int nt2 = 0; nt2 < 2; ++nt2) {
          f32x4 g = acc[mt2][nt2];
          float ig = sigf(g[0]);
          float fg = sigf(g[1]);
          float gg = tanh_c(g[2]);
          float og = sigf(g[3]);
          float c = fg * c1a[mt2][nt2] + ig * gg;
          c1a[mt2][nt2] = c;
          hh[nt2] = og * tanh_c(c);
        }
        unsigned int pk = pk_bf16(hh[0], hh[1]);
        int base = hbase[mt2] + 2 * ntp * 512;
        H1F[cur][base]       = (unsigned short)pk;
        H1F[cur][base + 512] = (unsigned short)(pk >> 16);
        int ob = obase[mt2] + 2 * ntp * 1088;
        OUTB[ob]        = (unsigned short)pk;
        OUTB[ob + 1088] = (unsigned short)(pk >> 16);
      }
    }
    if (t < Tq - 1) *(uint2*)(&XF[prv][0] + xfidx) = xv;
    __syncthreads();
  }
  {
    uint2 ov = *(const uint2*)(OUTB + outsrc);
    *(uint2*)(x2g + (Tq - 1) * 64) = ov;
  }
}

// ---------- K7: attention + MLP; dot2_f32_bf16 GEMVs, packed weights ----------
__global__ __launch_bounds__(512, 4) void k_attn(const unsigned short* __restrict__ x2,
    const unsigned short* __restrict__ WB, const float* __restrict__ wp,
    const float* __restrict__ pb2, const float* __restrict__ pb3,
    float* __restrict__ outp) {
  extern __shared__ char smem[];
  unsigned int* WLu = (unsigned int*)smem;
  int tid = threadIdx.x;
  int lane = tid & 63;
  int wid = tid >> 6;
  {
    const uint4* src = (const uint4*)WB;
    uint4* dstw = (uint4*)smem;
    for (int i = tid; i < 3072; i += 512)
      dstw[i] = src[(i < 512) ? i : i + 512];
  }
  char* wbase = smem + 49152 + wid * WAVE_SCR;
  unsigned short* xw = (unsigned short*)wbase;
  float* q = (float*)(wbase + 2304);
  unsigned int* op = (unsigned int*)(wbase + 2304);
  unsigned int* qkp = (unsigned int*)(wbase + 2560);
  unsigned int* hbp = qkp;
  float* pz = (float*)(wbase + 3104);
  unsigned int* z2p = (unsigned int*)(wbase + 3104);
  unsigned int* z1p = (unsigned int*)(wbase + 3360);
  int m = (blockIdx.x << 3) + wid;
  {
    const uint4* xp = (const uint4*)(x2 + (size_t)m * 1024);
    #pragma unroll
    for (int u = 0; u < 2; ++u) {
      uint4 pv = xp[lane * 2 + u];
      int f0 = (lane * 2 + u) * 8;
      int t = f0 >> 6, ch0 = f0 & 63;
      *(uint4*)(xw + t * 72 + ch0) = pv;
    }
  }
  __syncthreads();
  {
    const unsigned short* xr = xw + 15 * 72;
    float a0 = wp[O_QB + lane], a1 = 0.f, a2 = 0.f, a3 = 0.f;
    #pragma unroll
    for (int k2 = 0; k2 < 32; k2 += 4) {
      a0 = dot2bf(WLu[AQT_P + (k2 + 0) * 64 + lane], *(const unsigned int*)(xr + 2 * (k2 + 0)), a0);
      a1 = dot2bf(WLu[AQT_P + (k2 + 1) * 64 + lane], *(const unsigned int*)(xr + 2 * (k2 + 1)), a1);
      a2 = dot2bf(WLu[AQT_P + (k2 + 2) * 64 + lane], *(const unsigned int*)(xr + 2 * (k2 + 2)), a2);
      a3 = dot2bf(WLu[AQT_P + (k2 + 3) * 64 + lane], *(const unsigned int*)(xr + 2 * (k2 + 3)), a3);
    }
    q[lane] = (a0 + a1) + (a2 + a3);
  }
  #pragma unroll
  for (int h = 0; h < 4; ++h) {
    float a0 = 0.f, a1 = 0.f, a2 = 0.f, a3 = 0.f;
    #pragma unroll
    for (int d = 0; d < 16; d += 4) {
      a0 += bf2f(WB[WB_AWK + (h * 16 + d + 0) * 64 + lane]) * q[h * 16 + d + 0];
      a1 += bf2f(WB[WB_AWK + (h * 16 + d + 1) * 64 + lane]) * q[h * 16 + d + 1];
      a2 += bf2f(WB[WB_AWK + (h * 16 + d + 2) * 64 + lane]) * q[h * 16 + d + 2];
      a3 += bf2f(WB[WB_AWK + (h * 16 + d + 3) * 64 + lane]) * q[h * 16 + d + 3];
    }
    float a = (a0 + a1) + (a2 + a3);
    float an = __shfl_xor(a, 1);
    if (!(lane & 1)) qkp[h * 33 + (lane >> 1)] = pk_bf16(a, an);
  }
  {
    int hh = lane >> 4, tt = lane & 15;
    const unsigned short* xr = xw + tt * 72;
    float a0 = 0.f, a1 = 0.f, a2 = 0.f, a3 = 0.f;
    #pragma unroll
    for (int c2 = 0; c2 < 32; c2 += 4) {
      a0 = dot2bf(qkp[hh * 33 + c2 + 0], *(const unsigned int*)(xr + 2 * (c2 + 0)), a0);
      a1 = dot2bf(qkp[hh * 33 + c2 + 1], *(const unsigned int*)(xr + 2 * (c2 + 1)), a1);
      a2 = dot2bf(qkp[hh * 33 + c2 + 2], *(const unsigned int*)(xr + 2 * (c2 + 2)), a2);
      a3 = dot2bf(qkp[hh * 33 + c2 + 3], *(const unsigned int*)(xr + 2 * (c2 + 3)), a3);
    }
    float sc = (a0 + a1) + (a2 + a3);
    float mx = sc;
    mx = fmaxf(mx, __shfl_xor(mx, 1));
    mx = fmaxf(mx, __shfl_xor(mx, 2));
    mx = fmaxf(mx, __shfl_xor(mx, 4));
    mx = fmaxf(mx, __shfl_xor(mx, 8));
    float e = __expf(sc - mx);
    float sum = e;
    sum += __shfl_xor(sum, 1);
    sum += __shfl_xor(sum, 2);
    sum += __shfl_xor(sum, 4);
    sum += __shfl_xor(sum, 8);
    pz[lane] = e * rcpf(sum);
  }
  {
    float hb0 = 0.f, hb1 = 0.f, hb2 = 0.f, hb3 = 0.f;
    #pragma unroll
    for (int t = 0; t < 16; ++t) {
      float xv = bf2f(xw[t * 72 + lane]);
      hb0 += pz[t] * xv;
      hb1 += pz[16 + t] * xv;
      hb2 += pz[32 + t] * xv;
      hb3 += pz[48 + t] * xv;
    }
    float n0 = __shfl_xor(hb0, 1);
    float n1 = __shfl_xor(hb1, 1);
    float n2 = __shfl_xor(hb2, 1);
    float n3 = __shfl_xor(hb3, 1);
    if (!(lane & 1)) {
      int p = lane >> 1;
      hbp[p]          = pk_bf16(hb0, n0);
      hbp[33 + p]     = pk_bf16(hb1, n1);
      hbp[66 + p]     = pk_bf16(hb2, n2);
      hbp[99 + p]     = pk_bf16(hb3, n3);
    }
  }
  {
    int hsel = lane >> 4;
    float a0 = wp[O_VB + lane], a1 = 0.f, a2 = 0.f, a3 = 0.f;
    #pragma unroll
    for (int k2 = 0; k2 < 32; k2 += 4) {
      a0 = dot2bf(WLu[WVT_P + (k2 + 0) * 64 + lane], hbp[hsel * 33 + k2 + 0], a0);
      a1 = dot2bf(WLu[WVT_P + (k2 + 1) * 64 + lane], hbp[hsel * 33 + k2 + 1], a1);
      a2 = dot2bf(WLu[WVT_P + (k2 + 2) * 64 + lane], hbp[hsel * 33 + k2 + 2], a2);
      a3 = dot2bf(WLu[WVT_P + (k2 + 3) * 64 + lane], hbp[hsel * 33 + k2 + 3], a3);
    }
    float o = (a0 + a1) + (a2 + a3);
    float on = __shfl_xor(o, 1);
    if (!(lane & 1)) op[lane >> 1] = pk_bf16(o, on);
  }
  {
    float a0 = wp[O_B1P + lane], a1 = 0.f;
    float b0 = wp[O_B1P + 64 + lane], b1 = 0.f;
    #pragma unroll
    for (int k2 = 0; k2 < 32; k2 += 2) {
      unsigned int ov0 = op[k2], ov1 = op[k2 + 1];
      a0 = dot2bf(WLu[P1OW_P + (k2 + 0) * 128 + lane], ov0, a0);
      a1 = dot2bf(WLu[P1OW_P + (k2 + 1) * 128 + lane], ov1, a1);
      b0 = dot2bf(WLu[P1OW_P + (k2 + 0) * 128 + 64 + lane], ov0, b0);
      b1 = dot2bf(WLu[P1OW_P + (k2 + 1) * 128 + 64 + lane], ov1, b1);
    }
    float ra = fmaxf(a0 + a1, 0.f);
    float rb = fmaxf(b0 + b1, 0.f);
    float ran = __shfl_xor(ra, 1);
    float rbn = __shfl_xor(rb, 1);
    if (!(lane & 1)) {
      z1p[lane >> 1]      = pk_bf16(ra, ran);
      z1p[32 + (lane >> 1)] = pk_bf16(rb, rbn);
    }
  }
  {
    float a0 = pb2[lane], a1 = 0.f, a2 = 0.f, a3 = 0.f;
    #pragma unroll
    for (int k2 = 0; k2 < 64; k2 += 4) {
      a0 = dot2bf(WLu[P2T_P + (k2 + 0) * 64 + lane], z1p[k2 + 0], a0);
      a1 = dot2bf(WLu[P2T_P + (k2 + 1) * 64 + lane], z1p[k2 + 1], a1);
      a2 = dot2bf(WLu[P2T_P + (k2 + 2) * 64 + lane], z1p[k2 + 2], a2);
      a3 = dot2bf(WLu[P2T_P + (k2 + 3) * 64 + lane], z1p[k2 + 3], a3);
    }
    float z2 = fmaxf((a0 + a1) + (a2 + a3), 0.f);
    float zn = __shfl_xor(z2, 1);
    if (!(lane & 1)) z2p[lane >> 1] = pk_bf16(z2, zn);
  }
  {
    const unsigned int* p3 = (const unsigned int*)(WB + WB_P3T);
    int c = lane & 15;
    float a0 = (c < 13) ? pb3[c] : 0.f, a1 = 0.f, a2 = 0.f, a3 = 0.f;
    #pragma unroll
    for (int k2 = 0; k2 < 32; k2 += 4) {
      a0 = dot2bf(p3[(k2 + 0) * 16 + c], z2p[k2 + 0], a0);
      a1 = dot2bf(p3[(k2 + 1) * 16 + c], z2p[k2 + 1], a1);
      a2 = dot2bf(p3[(k2 + 2) * 16 + c], z2p[k2 + 2], a2);
      a3 = dot2bf(p3[(k2 + 3) * 16 + c], z2p[k2 + 3], a3);
    }
    if (lane < 13) outp[(size_t)m * 13 + lane] = (a0 + a1) + (a2 + a3);
  }
}

extern "C" void kernel_launch(void* const* d_in, const int* in_sizes, int n_in,
                              void* d_out, int out_size, void* d_ws, size_t ws_size,
                              hipStream_t stream) {
  (void)in_sizes; (void)n_in; (void)out_size; (void)ws_size;
  const float* nf   = (const float*)d_in[0];
  const int*   ei   = (const int*)d_in[1];
  const float* sw1  = (const float*)d_in[2];
  const float* sb1  = (const float*)d_in[3];
  const float* sw2  = (const float*)d_in[4];
  const float* sb2  = (const float*)d_in[5];
  const float* wih0 = (const float*)d_in[6];
  const float* whh0 = (const float*)d_in[7];
  const float* bih0 = (const float*)d_in[8];
  const float* bhh0 = (const float*)d_in[9];
  const float* wih1 = (const float*)d_in[10];
  const float* whh1 = (const float*)d_in[11];
  const float* bih1 = (const float*)d_in[12];
  const float* bhh1 = (const float*)d_in[13];
  const float* aw   = (const float*)d_in[14];
  const float* ab   = (const float*)d_in[15];
  const float* ow   = (const float*)d_in[16];
  const float* ob   = (const float*)d_in[17];
  const float* pw1  = (const float*)d_in[18];
  const float* pb1  = (const float*)d_in[19];
  const float* pw2  = (const float*)d_in[20];
  const float* pb2  = (const float*)d_in[21];
  const float* pw3  = (const float*)d_in[22];
  const float* pb3  = (const float*)d_in[23];

  char* ws = (char*)d_ws;
  float* wT = (float*)ws;                                   //   0 .. 384 KB
  unsigned short* WA = (unsigned short*)(ws + 393216);      // 384 KB (128 KB)
  unsigned short* WB = (unsigned short*)(ws + 458752);      // 448 KB (~58 KB)
  unsigned short* WE = (unsigned short*)(ws + 520192);      // ~508 KB (8 KB)
  int* rp   = (int*)(ws + 1048576);                         //   1 MB (~256 KB)
  int* col  = (int*)(ws + 1572864);                         // 1.5 MB (8 MB)
  unsigned short* henc = (unsigned short*)(ws + 10485760);  //  10 MB (32 MB)
  unsigned short* hmp  = (unsigned short*)(ws + 44040192);  //  42 MB (32 MB)
  int* bhist  = (int*)(ws + 44040192);   // 4 MB, aliases hmp (dead until k_mp)
  int* segoff = (int*)(ws + 48234496);   // 4 MB, aliases hmp (dead until k_mp)
  unsigned short* x2   = henc;           // alias: henc dead after k_mp
  float* outp = (float*)d_out;

  hipFuncSetAttribute((const void*)k_attn,
                      hipFuncAttributeMaxDynamicSharedMemorySize, SMEM_ATTN);
  k_prep<<<1, 256, 0, stream>>>(bih0, bhh0, bih1, bhh1, wT);
  k_prep_wa<<<256, 256, 0, stream>>>(wih0, whh0, wih1, whh1, WA);
  k_prep2<<<32, 256, 0, stream>>>(aw, ab, pw2, pw3, sw2, WB, WE, wT);
  k_prep3<<<32, 256, 0, stream>>>(pw1, ow, ob, pb1, WB, wT);
  k_enc<<<4096, 256, 0, stream>>>(nf, sw1, sb1, WE, sb2, henc);
  k_count<<<256, 1024, 0, stream>>>(ei, bhist);
  k_scan<<<16, 256, 0, stream>>>(bhist, rp, segoff);
  k_scatter<<<256, 1024, 0, stream>>>(ei, segoff, col);
  k_mp<<<16384, 256, 0, stream>>>(henc, rp, col, hmp);
  k_lstm<<<256, 1024, 0, stream>>>(hmp, WA, wT, x2);
  k_attn<<<2048, 512, SMEM_ATTN, stream>>>(x2, WB, wT, pb2, pb3, outp);
}

// Round 19
// 242.837 us; speedup vs baseline: 1.0560x; 1.0560x over previous
//
#include <hip/hip_runtime.h>

#define Bq 4
#define Tq 16
#define Nq 4096
#define NFq 8
#define Hq 64
#define Eq 131072
#define Cq 13
#define Mq (Bq*Nq)

typedef __attribute__((ext_vector_type(8))) short bf16x8;
typedef __attribute__((ext_vector_type(4))) float f32x4;

// ---------- helpers ----------
__device__ __forceinline__ float bf2f(unsigned short u) {
  return __uint_as_float(((unsigned int)u) << 16);
}
__device__ __forceinline__ unsigned short f2bf(float f) {
  unsigned int x = __float_as_uint(f);
  unsigned int r = x + 0x7fff + ((x >> 16) & 1);
  return (unsigned short)(r >> 16);
}
__device__ __forceinline__ float rcpf(float x) {
  float r;
  asm("v_rcp_f32 %0, %1" : "=v"(r) : "v"(x));
  return r;
}
__device__ __forceinline__ float sigf(float x) {
  return rcpf(1.f + __expf(-x));
}
__device__ __forceinline__ float tanh_c(float x) {
  float e = __expf(-2.f * x);
  return 2.f * rcpf(1.f + e) - 1.f;
}
__device__ __forceinline__ unsigned int pk_bf16(float lo, float hi) {
  unsigned int r;
  asm("v_cvt_pk_bf16_f32 %0, %1, %2" : "=v"(r) : "v"(lo), "v"(hi));
  return r;
}
__device__ __forceinline__ float dot2bf(unsigned int a, unsigned int b, float c) {
  float r;
  asm("v_dot2_f32_bf16 %0, %1, %2, %3" : "=v"(r) : "v"(a), "v"(b), "v"(c));
  return r;
}

// wT float offsets
#define O_BC0  65536
#define O_BC1  65792
#define O_QB   70144
#define O_VB   74304
#define O_B1P  95872

// WB (bf16 blob) ushort offsets (global). AQT/WVT/P1OW/P2T/P3T are k-PAIR-PACKED.
#define WB_AQT  0
#define WB_AWK  4096
#define WB_WVT  8192
#define WB_P1OW 12288
#define WB_P2T  20480
#define WB_P3T  28672
#define WB_TOT  29696

// k_attn LDS layout
#define AQT_P   0
#define WVT_P   2048
#define P1OW_P  4096
#define P2T_P   8192
#define WAVE_SCR 3648
#define SMEM_ATTN (49152 + 8 * WAVE_SCR)

// ---------- K0: LSTM bias combine ----------
__global__ __launch_bounds__(256) void k_prep(
    const float* __restrict__ bih0, const float* __restrict__ bhh0,
    const float* __restrict__ bih1, const float* __restrict__ bhh1,
    float* __restrict__ wT) {
  int i = threadIdx.x;
  wT[O_BC0 + i] = bih0[i] + bhh0[i];
  wT[O_BC1 + i] = bih1[i] + bhh1[i];
}

// ---------- K0a: pack LSTM weights into MFMA A-fragments, GATE-INTERLEAVED ----------
__global__ __launch_bounds__(256) void k_prep_wa(
    const float* __restrict__ wih0, const float* __restrict__ whh0,
    const float* __restrict__ wih1, const float* __restrict__ whh1,
    unsigned short* __restrict__ WA) {
  int i = blockIdx.x * 256 + threadIdx.x;    // 0..65535
  int j = i & 7, lane = (i >> 3) & 63, ks = (i >> 9) & 3;
  int mt = (i >> 11) & 15, L = (i >> 15) & 1;
  int rp = 16 * mt + (lane & 15);
  int orig = (rp & 3) * 64 + (rp >> 2);      // gate-major original row
  int k = 32 * ks + 8 * (lane >> 4) + j;
  const float* w = L ? (k < 64 ? wih1 : whh1) : (k < 64 ? wih0 : whh0);
  WA[i] = f2bf(w[orig * 64 + (k & 63)]);
}

// ---------- K0b: attention weight pack + encoder w2 A-frag pack ----------
__global__ __launch_bounds__(256) void k_prep2(
    const float* __restrict__ aw, const float* __restrict__ ab,
    const float* __restrict__ pw2, const float* __restrict__ pw3,
    const float* __restrict__ sw2,
    unsigned short* __restrict__ WBu, unsigned short* __restrict__ WE,
    float* __restrict__ wT) {
  int i = blockIdx.x * 256 + threadIdx.x;   // 0..8191
  if (i < 4096) {
    int k = i >> 6, ch = i & 63;
    int pidx = (k >> 1) * 128 + ch * 2 + (k & 1);
    WBu[WB_AQT + pidx] = f2bf(0.25f * aw[ch * 64 + k]);   // Aq^T, scale folded
    WBu[WB_AWK + i]    = f2bf(aw[(64 + k) * 64 + ch]);    // Wk rows (element order)
    WBu[WB_WVT + pidx] = f2bf(aw[(128 + ch) * 64 + k]);   // Wv^T
    int e = i & 7, l = (i >> 3) & 63, eks = (i >> 9) & 1, mt = i >> 10;
    WE[i] = f2bf(sw2[(mt * 16 + (l & 15)) * 64 + 32 * eks + 8 * (l >> 4) + e]);
  }
  {
    int k = i >> 6, j = i & 63;                            // P2T k<128
    int pidx = (k >> 1) * 128 + j * 2 + (k & 1);
    WBu[WB_P2T + pidx] = f2bf(pw2[j * 128 + k]);
  }
  if (i < 1024) {
    int k = i >> 4, c = i & 15;
    int pidx = (k >> 1) * 32 + c * 2 + (k & 1);
    WBu[WB_P3T + pidx] = (c < 13) ? f2bf(pw3[c * 64 + k]) : (unsigned short)0;
  }
  if (i < 64) {
    wT[O_QB + i] = 0.25f * ab[i];
    wT[O_VB + i] = ab[128 + i];
  }
}

// ---------- K0c: fold out-projection into pw1 (k-pair-packed) ----------
__global__ __launch_bounds__(256) void k_prep3(
    const float* __restrict__ pw1, const float* __restrict__ ow,
    const float* __restrict__ ob, const float* __restrict__ pb1,
    unsigned short* __restrict__ WBu, float* __restrict__ wT) {
  int i = blockIdx.x * 256 + threadIdx.x;  // 0..8191
  int j = i >> 6, k = i & 63;
  float s0 = 0.f, s1 = 0.f, s2 = 0.f, s3 = 0.f;
  for (int m2 = 0; m2 < 64; m2 += 4) {
    s0 += pw1[j * 64 + m2]     * ow[m2 * 64 + k];
    s1 += pw1[j * 64 + m2 + 1] * ow[(m2 + 1) * 64 + k];
    s2 += pw1[j * 64 + m2 + 2] * ow[(m2 + 2) * 64 + k];
    s3 += pw1[j * 64 + m2 + 3] * ow[(m2 + 3) * 64 + k];
  }
  WBu[WB_P1OW + (k >> 1) * 256 + j * 2 + (k & 1)] = f2bf((s0 + s1) + (s2 + s3));
  if (k == 0) {
    float b = pb1[j];
    for (int m2 = 0; m2 < 64; ++m2) b += pw1[j * 64 + m2] * ob[m2];
    wT[O_B1P + j] = b;
  }
}

// ---------- K1: spatial encoder — layer1 f32, layer2 MFMA ----------
__global__ __launch_bounds__(256) void k_enc(
    const float* __restrict__ nf, const float* __restrict__ w1,
    const float* __restrict__ b1, const unsigned short* __restrict__ WE,
    const float* __restrict__ b2, unsigned short* __restrict__ henc) {
  __shared__ float xr[64][9];
  __shared__ unsigned short H1F[4096];
  __shared__ unsigned short OUT[64 * 72];
  int tid = threadIdx.x;
  int lane = tid & 63;
  int wv = tid >> 6;
  size_t row0 = (size_t)blockIdx.x * 64;
  {
    float2 v = ((const float2*)(nf + row0 * 8))[tid];
    int r = tid >> 2, q = tid & 3;
    xr[r][q * 2] = v.x;
    xr[r][q * 2 + 1] = v.y;
  }
  bf16x8 afr0, afr1;
  {
    const bf16x8* we8 = (const bf16x8*)WE;
    afr0 = we8[(wv * 2 + 0) * 64 + lane];
    afr1 = we8[(wv * 2 + 1) * 64 + lane];
  }
  int chb = wv * 16 + (lane >> 4) * 4;
  float4 b2v;
  b2v.x = b2[chb]; b2v.y = b2[chb + 1]; b2v.z = b2[chb + 2]; b2v.w = b2[chb + 3];
  __syncthreads();
  {
    int r = lane;
    float x0 = xr[r][0], x1 = xr[r][1], x2v = xr[r][2], x3 = xr[r][3];
    float x4 = xr[r][4], x5 = xr[r][5], x6 = xr[r][6], x7 = xr[r][7];
    #pragma unroll
    for (int run = 0; run < 2; ++run) {
      unsigned int pk4[4];
      #pragma unroll
      for (int p = 0; p < 4; ++p) {
        int j0 = wv * 16 + run * 8 + p * 2;
        const float* wr0 = w1 + j0 * 8;
        const float* wr1 = wr0 + 8;
        float a0 = b1[j0]     + wr0[0]*x0 + wr0[1]*x1 + wr0[2]*x2v + wr0[3]*x3
                              + wr0[4]*x4 + wr0[5]*x5 + wr0[6]*x6 + wr0[7]*x7;
        float a1 = b1[j0 + 1] + wr1[0]*x0 + wr1[1]*x1 + wr1[2]*x2v + wr1[3]*x3
                              + wr1[4]*x4 + wr1[5]*x5 + wr1[6]*x6 + wr1[7]*x7;
        pk4[p] = pk_bf16(fmaxf(a0, 0.f), fmaxf(a1, 0.f));
      }
      int jb = wv * 16 + run * 8;
      int ks = jb >> 5;
      int l2 = (lane & 15) | (((jb >> 3) & 3) << 4);
      int nt = lane >> 4;
      uint4 v; v.x = pk4[0]; v.y = pk4[1]; v.z = pk4[2]; v.w = pk4[3];
      *(uint4*)(&H1F[((ks * 4 + nt) * 64 + l2) * 8]) = v;
    }
  }
  __syncthreads();
  {
    #pragma unroll
    for (int nt = 0; nt < 4; ++nt) {
      f32x4 acc = (f32x4){b2v.x, b2v.y, b2v.z, b2v.w};
      bf16x8 bf0 = *(const bf16x8*)(&H1F[((0 * 4 + nt) * 64 + lane) * 8]);
      bf16x8 bf1 = *(const bf16x8*)(&H1F[((1 * 4 + nt) * 64 + lane) * 8]);
      acc = __builtin_amdgcn_mfma_f32_16x16x32_bf16(afr0, bf0, acc, 0, 0, 0);
      acc = __builtin_amdgcn_mfma_f32_16x16x32_bf16(afr1, bf1, acc, 0, 0, 0);
      int orow = nt * 16 + (lane & 15);
      uint2 pv;
      pv.x = pk_bf16(acc[0], acc[1]);
      pv.y = pk_bf16(acc[2], acc[3]);
      *(uint2*)(&OUT[orow * 72 + chb]) = pv;
    }
  }
  __syncthreads();
  {
    int rr = tid >> 2, part = tid & 3;
    uint4 v0 = *(uint4*)(&OUT[rr * 72 + part * 16]);
    uint4 v1 = *(uint4*)(&OUT[rr * 72 + part * 16 + 8]);
    *(uint4*)(henc + (row0 + rr) * 64 + part * 16) = v0;
    *(uint4*)(henc + (row0 + rr) * 64 + part * 16 + 8) = v1;
  }
}

// ---------- K2: per-block LDS histogram (NO global atomics) ----------
__global__ __launch_bounds__(1024) void k_count(const int* __restrict__ ei,
                                                int* __restrict__ bhist) {
  __shared__ int hist[4096];
  int b = blockIdx.x;
  int t = b & 15, seg = b >> 4;
  int tid = threadIdx.x;
  #pragma unroll
  for (int i = tid; i < 4096; i += 1024) hist[i] = 0;
  __syncthreads();
  const int* dstp = ei + ((t << 1) + 1) * Eq + (seg << 13);
  #pragma unroll
  for (int u = 0; u < 8; ++u) {
    int dst = dstp[(u << 10) + tid];
    atomicAdd(&hist[dst], 1);
  }
  __syncthreads();
  int* op = bhist + (b << 12);
  #pragma unroll
  for (int i = tid; i < 4096; i += 1024) op[i] = hist[i];
}

// ---------- K3: scan -> rp + per-segment bases segoff[t*16+seg][node] ----------
__global__ __launch_bounds__(256) void k_scan(const int* __restrict__ bhist,
                                              int* __restrict__ rp,
                                              int* __restrict__ segoff) {
  int t = blockIdx.x, tid = threadIdx.x;
  __shared__ int part[256];
  int loc[16];
  int s = 0;
  #pragma unroll
  for (int j = 0; j < 16; ++j) {
    int node = tid * 16 + j;
    int v = 0;
    #pragma unroll
    for (int seg = 0; seg < 16; ++seg)
      v += bhist[((t + (seg << 4)) << 12) + node];
    loc[j] = v;
    s += v;
  }
  part[tid] = s;
  __syncthreads();
  if (tid == 0) {
    int run = 0;
    for (int i2 = 0; i2 < 256; ++i2) { int v = part[i2]; part[i2] = run; run += v; }
  }
  __syncthreads();
  int off = part[tid];
  #pragma unroll
  for (int j = 0; j < 16; ++j) {
    int node = tid * 16 + j;
    rp[t * (Nq + 1) + node] = off;
    int running = off;
    #pragma unroll
    for (int seg = 0; seg < 16; ++seg) {
      segoff[(((t << 4) + seg) << 12) + node] = running;
      running += bhist[((t + (seg << 4)) << 12) + node];
    }
    off += loc[j];
  }
  if (tid == 255) rp[t * (Nq + 1) + Nq] = off;
}

// ---------- K4: scatter via LDS positions (no global atomics) ----------
__global__ __launch_bounds__(1024) void k_scatter(const int* __restrict__ ei,
    const int* __restrict__ segoff, int* __restrict__ col) {
  __shared__ int loff[4096];
  int b = blockIdx.x;                      // 256
  int t = b & 15, seg = b >> 4;
  int tid = threadIdx.x;
  for (int i = tid; i < 4096; i += 1024)
    loff[i] = segoff[(((t << 4) + seg) << 12) + i];
  __syncthreads();
  const int* srcp = ei + (t << 1) * Eq + (seg << 13);
  const int* dstp = ei + ((t << 1) + 1) * Eq + (seg << 13);
  #pragma unroll
  for (int u = 0; u < 8; ++u) {
    int e = (u << 10) + tid;
    int src = srcp[e];
    int dst = dstp[e];
    int pos = atomicAdd(&loff[dst], 1);
    col[(t << 17) + pos] = src;
  }
}

// ---------- K5: message passing; t PHASE-PARTITIONED per XCD (1 slab live) ----------
__global__ __launch_bounds__(256) void k_mp(const unsigned short* __restrict__ henc,
    const int* __restrict__ rp, const int* __restrict__ col,
    unsigned short* __restrict__ hmp) {
  int lane = threadIdx.x & 63;
  int bkk = blockIdx.x;                    // 16384
  // phase partition: blocks [0,8K) do t=0..7 (XCD x <- t=x), [8K,16K) do t=8..15
  int t = (bkk & 7) | ((bkk >> 13) << 3);
  int n = ((bkk >> 3) & 1023) * 4 + __builtin_amdgcn_readfirstlane(threadIdx.x >> 6);
  const int* rpt = rp + t * (Nq + 1);
  const int* colt = col + (t << 17);
  int e0 = rpt[n], e1 = rpt[n + 1];
  int half = lane >> 5;
  int b2 = (lane >> 3) & 3;
  int c8 = (lane & 7) << 3;
  const unsigned short* hb2 = henc + (size_t)b2 * 4194304 + t * 262144 + c8;
  float acc[8] = {0.f, 0.f, 0.f, 0.f, 0.f, 0.f, 0.f, 0.f};
  int e = e0;
  for (; e + 8 <= e1; e += 8) {
    int i0 = colt[e + half];
    int i1 = colt[e + 2 + half];
    int i2 = colt[e + 4 + half];
    int i3 = colt[e + 6 + half];
    uint4 p0 = *(const uint4*)(hb2 + i0 * 64);
    uint4 p1 = *(const uint4*)(hb2 + i1 * 64);
    uint4 p2 = *(const uint4*)(hb2 + i2 * 64);
    uint4 p3 = *(const uint4*)(hb2 + i3 * 64);
    acc[0] += bf2f((unsigned short)(p0.x & 0xffff)) + bf2f((unsigned short)(p1.x & 0xffff))
            + bf2f((unsigned short)(p2.x & 0xffff)) + bf2f((unsigned short)(p3.x & 0xffff));
    acc[1] += bf2f((unsigned short)(p0.x >> 16)) + bf2f((unsigned short)(p1.x >> 16))
            + bf2f((unsigned short)(p2.x >> 16)) + bf2f((unsigned short)(p3.x >> 16));
    acc[2] += bf2f((unsigned short)(p0.y & 0xffff)) + bf2f((unsigned short)(p1.y & 0xffff))
            + bf2f((unsigned short)(p2.y & 0xffff)) + bf2f((unsigned short)(p3.y & 0xffff));
    acc[3] += bf2f((unsigned short)(p0.y >> 16)) + bf2f((unsigned short)(p1.y >> 16))
            + bf2f((unsigned short)(p2.y >> 16)) + bf2f((unsigned short)(p3.y >> 16));
    acc[4] += bf2f((unsigned short)(p0.z & 0xffff)) + bf2f((unsigned short)(p1.z & 0xffff))
            + bf2f((unsigned short)(p2.z & 0xffff)) + bf2f((unsigned short)(p3.z & 0xffff));
    acc[5] += bf2f((unsigned short)(p0.z >> 16)) + bf2f((unsigned short)(p1.z >> 16))
            + bf2f((unsigned short)(p2.z >> 16)) + bf2f((unsigned short)(p3.z >> 16));
    acc[6] += bf2f((unsigned short)(p0.w & 0xffff)) + bf2f((unsigned short)(p1.w & 0xffff))
            + bf2f((unsigned short)(p2.w & 0xffff)) + bf2f((unsigned short)(p3.w & 0xffff));
    acc[7] += bf2f((unsigned short)(p0.w >> 16)) + bf2f((unsigned short)(p1.w >> 16))
            + bf2f((unsigned short)(p2.w >> 16)) + bf2f((unsigned short)(p3.w >> 16));
  }
  if (half == 0) {
    for (; e < e1; ++e) {
      int i0 = colt[e];
      uint4 p0 = *(const uint4*)(hb2 + i0 * 64);
      acc[0] += bf2f((unsigned short)(p0.x & 0xffff));
      acc[1] += bf2f((unsigned short)(p0.x >> 16));
      acc[2] += bf2f((unsigned short)(p0.y & 0xffff));
      acc[3] += bf2f((unsigned short)(p0.y >> 16));
      acc[4] += bf2f((unsigned short)(p0.z & 0xffff));
      acc[5] += bf2f((unsigned short)(p0.z >> 16));
      acc[6] += bf2f((unsigned short)(p0.w & 0xffff));
      acc[7] += bf2f((unsigned short)(p0.w >> 16));
    }
  }
  #pragma unroll
  for (int i = 0; i < 8; ++i) acc[i] += __shfl_xor(acc[i], 32);
  uint4 ps = *(const uint4*)(hb2 + n * 64);
  int deg = e1 - e0;
  if (half == 0) {
    uint4 out;
    if (deg > 0) {
      float sc = 0.5f * rcpf((float)deg);
      float s0 = bf2f((unsigned short)(ps.x & 0xffff)) * 0.5f + acc[0] * sc;
      float s1 = bf2f((unsigned short)(ps.x >> 16))    * 0.5f + acc[1] * sc;
      float s2 = bf2f((unsigned short)(ps.y & 0xffff)) * 0.5f + acc[2] * sc;
      float s3 = bf2f((unsigned short)(ps.y >> 16))    * 0.5f + acc[3] * sc;
      float s4 = bf2f((unsigned short)(ps.z & 0xffff)) * 0.5f + acc[4] * sc;
      float s5 = bf2f((unsigned short)(ps.z >> 16))    * 0.5f + acc[5] * sc;
      float s6 = bf2f((unsigned short)(ps.w & 0xffff)) * 0.5f + acc[6] * sc;
      float s7 = bf2f((unsigned short)(ps.w >> 16))    * 0.5f + acc[7] * sc;
      out.x = pk_bf16(s0, s1);
      out.y = pk_bf16(s2, s3);
      out.z = pk_bf16(s4, s5);
      out.w = pk_bf16(s6, s7);
    } else {
      out = ps;
    }
    *(uint4*)(hmp + (size_t)b2 * 4194304 + t * 262144 + n * 64 + c8) = out;
  }
}

// ---------- K6: fused 2-layer LSTM; 64 seqs/block, 2-barrier pipelined steps ----------
__global__ __launch_bounds__(1024) void k_lstm(
    const unsigned short* __restrict__ hmp,
    const unsigned short* __restrict__ WA,
    const float* __restrict__ wT,
    unsigned short* __restrict__ x2) {
  __shared__ unsigned short XF[2][4096];
  __shared__ unsigned short H0F[2][4096];
  __shared__ unsigned short H1F[2][4096];
  __shared__ unsigned short OUTB[64 * 68];
  int tid = threadIdx.x;
  int l = tid & 63;
  int w = tid >> 6;
  int mtp = w >> 1, ntp = w & 1;
  int m0 = blockIdx.x << 6;

  bf16x8 afr[2][2][4];
  const bf16x8* wa8 = (const bf16x8*)WA;
  #pragma unroll
  for (int L = 0; L < 2; ++L)
    #pragma unroll
    for (int mt2 = 0; mt2 < 2; ++mt2)
      #pragma unroll
      for (int ks = 0; ks < 4; ++ks)
        afr[L][mt2][ks] = wa8[((L * 16 + (2 * mtp + mt2)) * 4 + ks) * 64 + l];

  float4 bias0[2], bias1[2];
  int hbase[2], obase[2];
  #pragma unroll
  for (int mt2 = 0; mt2 < 2; ++mt2) {
    int ch = 4 * (2 * mtp + mt2) + (l >> 4);
    bias0[mt2].x = wT[O_BC0 + ch];       bias0[mt2].y = wT[O_BC0 + 64 + ch];
    bias0[mt2].z = wT[O_BC0 + 128 + ch]; bias0[mt2].w = wT[O_BC0 + 192 + ch];
    bias1[mt2].x = wT[O_BC1 + ch];       bias1[mt2].y = wT[O_BC1 + 64 + ch];
    bias1[mt2].z = wT[O_BC1 + 128 + ch]; bias1[mt2].w = wT[O_BC1 + 192 + ch];
    int l2 = (l & 15) | (((ch >> 3) & 3) << 4);
    hbase[mt2] = (ch >> 5) * 2048 + l2 * 8 + (ch & 7);
    obase[mt2] = (l & 15) * 68 + ch;
  }
  float c0a[2][2] = {{0.f, 0.f}, {0.f, 0.f}};
  float c1a[2][2] = {{0.f, 0.f}, {0.f, 0.f}};

  int sA = tid >> 4, c4 = (tid & 15) << 2;
  int xfidx = (((c4 >> 5) * 4 + (sA >> 4)) * 64 + ((sA & 15) | (((c4 >> 3) & 3) << 4))) * 8 + (c4 & 7);
  int mm = m0 + sA;
  int bb = mm >> 12, nn = mm & 4095;
  const unsigned short* srcb = hmp + ((size_t)(bb * 16) * 4096 + (size_t)nn) * 64 + c4;
  unsigned short* x2g = x2 + (size_t)mm * (Tq * Hq) + c4;
  int outsrc = sA * 68 + c4;

  int* hz0 = (int*)&H0F[1][0];
  int* hz1 = (int*)&H1F[1][0];
  for (int i = tid; i < 2048; i += 1024) { hz0[i] = 0; hz1[i] = 0; }

  uint2 xv = *(const uint2*)srcb;
  *(uint2*)(&XF[0][0] + xfidx) = xv;
  __syncthreads();

  for (int t = 0; t < Tq; ++t) {
    int cur = t & 1, prv = cur ^ 1;

    if (t > 0) {
      uint2 ov = *(const uint2*)(OUTB + outsrc);
      *(uint2*)(x2g + (t - 1) * 64) = ov;
    }
    if (t < Tq - 1) xv = *(const uint2*)(srcb + (t + 1) * 262144);
    {
      f32x4 acc[2][2];
      #pragma unroll
      for (int mt2 = 0; mt2 < 2; ++mt2)
        #pragma unroll
        for (int nt2 = 0; nt2 < 2; ++nt2) {
          float4 bv = bias0[mt2];
          acc[mt2][nt2] = (f32x4){bv.x, bv.y, bv.z, bv.w};
        }
      #pragma unroll
      for (int nt2 = 0; nt2 < 2; ++nt2) {
        int nt = 2 * ntp + nt2;
        #pragma unroll
        for (int ks = 0; ks < 4; ++ks) {
          const unsigned short* bs = (ks < 2) ? &XF[cur][0] : &H0F[prv][0];
          bf16x8 bf = *(const bf16x8*)(bs + (((ks & 1) * 4 + nt) * 64 + l) * 8);
          acc[0][nt2] = __builtin_amdgcn_mfma_f32_16x16x32_bf16(afr[0][0][ks], bf, acc[0][nt2], 0, 0, 0);
          acc[1][nt2] = __builtin_amdgcn_mfma_f32_16x16x32_bf16(afr[0][1][ks], bf, acc[1][nt2], 0, 0, 0);
        }
      }
      #pragma unroll
      for (int mt2 = 0; mt2 < 2; ++mt2) {
        float hh[2];
        #pragma unroll
        for (int nt2 = 0; nt2 < 2; ++nt2) {
          f32x4 g = acc[mt2][nt2];
          float ig = sigf(g[0]);
          float fg = sigf(g[1]);
          float gg = tanh_c(g[2]);
          float og = sigf(g[3]);
          float c = fg * c0a[mt2][nt2] + ig * gg;
          c0a[mt2][nt2] = c;
          hh[nt2] = og * tanh_c(c);
        }
        unsigned int pk = pk_bf16(hh[0], hh[1]);
        int base = hbase[mt2] + 2 * ntp * 512;
        H0F[cur][base]       = (unsigned short)pk;
        H0F[cur][base + 512] = (unsigned short)(pk >> 16);
      }
    }
    __syncthreads();

    {
      f32x4 acc[2][2];
      #pragma unroll
      for (int mt2 = 0; mt2 < 2; ++mt2)
        #pragma unroll
        for (int nt2 = 0; nt2 < 2; ++nt2) {
          float4 bv = bias1[mt2];
          acc[mt2][nt2] = (f32x4){bv.x, bv.y, bv.z, bv.w};
        }
      #pragma unroll
      for (int nt2 = 0; nt2 < 2; ++nt2) {
        int nt = 2 * ntp + nt2;
        #pragma unroll
        for (int ks = 0; ks < 4; ++ks) {
          const unsigned short* bs = (ks < 2) ? &H0F[cur][0] : &H1F[prv][0];
          bf16x8 bf = *(const bf16x8*)(bs + (((ks & 1) * 4 + nt) * 64 + l) * 8);
          acc[0][nt2] = __builtin_amdgcn_mfma_f32_16x16x32_bf16(afr[1][0][ks], bf, acc[0][nt2], 0, 0, 0);
          acc[1][nt2] = __builtin_amdgcn_mfma_f32_16x16x32_bf16(afr[1][1][ks], bf, acc[1][nt2], 0, 0, 0);
        }
      }
      #pragma unroll
      for (int mt2 = 0; mt2 < 2; ++mt2) {
        float hh[2];
        #pragma unroll
        for (int nt2 = 0; nt2 < 2; ++nt2) {
          f32x4 g = acc[mt2][nt2];
          float ig = sigf(g[0]);
          float fg = sigf(g[1]);
          float gg = tanh_c(g[2]);
          float og = sigf(g[3]);
          float c = fg * c1a[mt2][nt2] + ig * gg;
          c1a[mt2][nt2] = c;
          hh[nt2] = og * tanh_c(c);
        }
        unsigned int pk = pk_bf16(hh[0], hh[1]);
        int base = hbase[mt2] + 2 * ntp * 512;
        H1F[cur][base]       = (unsigned short)pk;
        H1F[cur][base + 512] = (unsigned short)(pk >> 16);
        int ob = obase[mt2] + 2 * ntp * 1088;
        OUTB[ob]        = (unsigned short)pk;
        OUTB[ob + 1088] = (unsigned short)(pk >> 16);
      }
    }
    if (t < Tq - 1) *(uint2*)(&XF[prv][0] + xfidx) = xv;
    __syncthreads();
  }
  {
    uint2 ov = *(const uint2*)(OUTB + outsrc);
    *(uint2*)(x2g + (Tq - 1) * 64) = ov;
  }
}

// ---------- K7: attention + MLP; dot2_f32_bf16 GEMVs, packed weights ----------
__global__ __launch_bounds__(512, 4) void k_attn(const unsigned short* __restrict__ x2,
    const unsigned short* __restrict__ WB, const float* __restrict__ wp,
    const float* __restrict__ pb2, const float* __restrict__ pb3,
    float* __restrict__ outp) {
  extern __shared__ char smem[];
  unsigned int* WLu = (unsigned int*)smem;
  int tid = threadIdx.x;
  int lane = tid & 63;
  int wid = tid >> 6;
  {
    const uint4* src = (const uint4*)WB;
    uint4* dstw = (uint4*)smem;
    for (int i = tid; i < 3072; i += 512)
      dstw[i] = src[(i < 512) ? i : i + 512];
  }
  char* wbase = smem + 49152 + wid * WAVE_SCR;
  unsigned short* xw = (unsigned short*)wbase;
  float* q = (float*)(wbase + 2304);
  unsigned int* op = (unsigned int*)(wbase + 2304);
  unsigned int* qkp = (unsigned int*)(wbase + 2560);
  unsigned int* hbp = qkp;
  float* pz = (float*)(wbase + 3104);
  unsigned int* z2p = (unsigned int*)(wbase + 3104);
  unsigned int* z1p = (unsigned int*)(wbase + 3360);
  int m = (blockIdx.x << 3) + wid;
  {
    const uint4* xp = (const uint4*)(x2 + (size_t)m * 1024);
    #pragma unroll
    for (int u = 0; u < 2; ++u) {
      uint4 pv = xp[lane * 2 + u];
      int f0 = (lane * 2 + u) * 8;
      int t = f0 >> 6, ch0 = f0 & 63;
      *(uint4*)(xw + t * 72 + ch0) = pv;
    }
  }
  __syncthreads();
  {
    const unsigned short* xr = xw + 15 * 72;
    float a0 = wp[O_QB + lane], a1 = 0.f, a2 = 0.f, a3 = 0.f;
    #pragma unroll
    for (int k2 = 0; k2 < 32; k2 += 4) {
      a0 = dot2bf(WLu[AQT_P + (k2 + 0) * 64 + lane], *(const unsigned int*)(xr + 2 * (k2 + 0)), a0);
      a1 = dot2bf(WLu[AQT_P + (k2 + 1) * 64 + lane], *(const unsigned int*)(xr + 2 * (k2 + 1)), a1);
      a2 = dot2bf(WLu[AQT_P + (k2 + 2) * 64 + lane], *(const unsigned int*)(xr + 2 * (k2 + 2)), a2);
      a3 = dot2bf(WLu[AQT_P + (k2 + 3) * 64 + lane], *(const unsigned int*)(xr + 2 * (k2 + 3)), a3);
    }
    q[lane] = (a0 + a1) + (a2 + a3);
  }
  #pragma unroll
  for (int h = 0; h < 4; ++h) {
    float a0 = 0.f, a1 = 0.f, a2 = 0.f, a3 = 0.f;
    #pragma unroll
    for (int d = 0; d < 16; d += 4) {
      a0 += bf2f(WB[WB_AWK + (h * 16 + d + 0) * 64 + lane]) * q[h * 16 + d + 0];
      a1 += bf2f(WB[WB_AWK + (h * 16 + d + 1) * 64 + lane]) * q[h * 16 + d + 1];
      a2 += bf2f(WB[WB_AWK + (h * 16 + d + 2) * 64 + lane]) * q[h * 16 + d + 2];
      a3 += bf2f(WB[WB_AWK + (h * 16 + d + 3) * 64 + lane]) * q[h * 16 + d + 3];
    }
    float a = (a0 + a1) + (a2 + a3);
    float an = __shfl_xor(a, 1);
    if (!(lane & 1)) qkp[h * 33 + (lane >> 1)] = pk_bf16(a, an);
  }
  {
    int hh = lane >> 4, tt = lane & 15;
    const unsigned short* xr = xw + tt * 72;
    float a0 = 0.f, a1 = 0.f, a2 = 0.f, a3 = 0.f;
    #pragma unroll
    for (int c2 = 0; c2 < 32; c2 += 4) {
      a0 = dot2bf(qkp[hh * 33 + c2 + 0], *(const unsigned int*)(xr + 2 * (c2 + 0)), a0);
      a1 = dot2bf(qkp[hh * 33 + c2 + 1], *(const unsigned int*)(xr + 2 * (c2 + 1)), a1);
      a2 = dot2bf(qkp[hh * 33 + c2 + 2], *(const unsigned int*)(xr + 2 * (c2 + 2)), a2);
      a3 = dot2bf(qkp[hh * 33 + c2 + 3], *(const unsigned int*)(xr + 2 * (c2 + 3)), a3);
    }
    float sc = (a0 + a1) + (a2 + a3);
    float mx = sc;
    mx = fmaxf(mx, __shfl_xor(mx, 1));
    mx = fmaxf(mx, __shfl_xor(mx, 2));
    mx = fmaxf(mx, __shfl_xor(mx, 4));
    mx = fmaxf(mx, __shfl_xor(mx, 8));
    float e = __expf(sc - mx);
    float sum = e;
    sum += __shfl_xor(sum, 1);
    sum += __shfl_xor(sum, 2);
    sum += __shfl_xor(sum, 4);
    sum += __shfl_xor(sum, 8);
    pz[lane] = e * rcpf(sum);
  }
  {
    float hb0 = 0.f, hb1 = 0.f, hb2 = 0.f, hb3 = 0.f;
    #pragma unroll
    for (int t = 0; t < 16; ++t) {
      float xv = bf2f(xw[t * 72 + lane]);
      hb0 += pz[t] * xv;
      hb1 += pz[16 + t] * xv;
      hb2 += pz[32 + t] * xv;
      hb3 += pz[48 + t] * xv;
    }
    float n0 = __shfl_xor(hb0, 1);
    float n1 = __shfl_xor(hb1, 1);
    float n2 = __shfl_xor(hb2, 1);
    float n3 = __shfl_xor(hb3, 1);
    if (!(lane & 1)) {
      int p = lane >> 1;
      hbp[p]          = pk_bf16(hb0, n0);
      hbp[33 + p]     = pk_bf16(hb1, n1);
      hbp[66 + p]     = pk_bf16(hb2, n2);
      hbp[99 + p]     = pk_bf16(hb3, n3);
    }
  }
  {
    int hsel = lane >> 4;
    float a0 = wp[O_VB + lane], a1 = 0.f, a2 = 0.f, a3 = 0.f;
    #pragma unroll
    for (int k2 = 0; k2 < 32; k2 += 4) {
      a0 = dot2bf(WLu[WVT_P + (k2 + 0) * 64 + lane], hbp[hsel * 33 + k2 + 0], a0);
      a1 = dot2bf(WLu[WVT_P + (k2 + 1) * 64 + lane], hbp[hsel * 33 + k2 + 1], a1);
      a2 = dot2bf(WLu[WVT_P + (k2 + 2) * 64 + lane], hbp[hsel * 33 + k2 + 2], a2);
      a3 = dot2bf(WLu[WVT_P + (k2 + 3) * 64 + lane], hbp[hsel * 33 + k2 + 3], a3);
    }
    float o = (a0 + a1) + (a2 + a3);
    float on = __shfl_xor(o, 1);
    if (!(lane & 1)) op[lane >> 1] = pk_bf16(o, on);
  }
  {
    float a0 = wp[O_B1P + lane], a1 = 0.f;
    float b0 = wp[O_B1P + 64 + lane], b1 = 0.f;
    #pragma unroll
    for (int k2 = 0; k2 < 32; k2 += 2) {
      unsigned int ov0 = op[k2], ov1 = op[k2 + 1];
      a0 = dot2bf(WLu[P1OW_P + (k2 + 0) * 128 + lane], ov0, a0);
      a1 = dot2bf(WLu[P1OW_P + (k2 + 1) * 128 + lane], ov1, a1);
      b0 = dot2bf(WLu[P1OW_P + (k2 + 0) * 128 + 64 + lane], ov0, b0);
      b1 = dot2bf(WLu[P1OW_P + (k2 + 1) * 128 + 64 + lane], ov1, b1);
    }
    float ra = fmaxf(a0 + a1, 0.f);
    float rb = fmaxf(b0 + b1, 0.f);
    float ran = __shfl_xor(ra, 1);
    float rbn = __shfl_xor(rb, 1);
    if (!(lane & 1)) {
      z1p[lane >> 1]      = pk_bf16(ra, ran);
      z1p[32 + (lane >> 1)] = pk_bf16(rb, rbn);
    }
  }
  {
    float a0 = pb2[lane], a1 = 0.f, a2 = 0.f, a3 = 0.f;
    #pragma unroll
    for (int k2 = 0; k2 < 64; k2 += 4) {
      a0 = dot2bf(WLu[P2T_P + (k2 + 0) * 64 + lane], z1p[k2 + 0], a0);
      a1 = dot2bf(WLu[P2T_P + (k2 + 1) * 64 + lane], z1p[k2 + 1], a1);
      a2 = dot2bf(WLu[P2T_P + (k2 + 2) * 64 + lane], z1p[k2 + 2], a2);
      a3 = dot2bf(WLu[P2T_P + (k2 + 3) * 64 + lane], z1p[k2 + 3], a3);
    }
    float z2 = fmaxf((a0 + a1) + (a2 + a3), 0.f);
    float zn = __shfl_xor(z2, 1);
    if (!(lane & 1)) z2p[lane >> 1] = pk_bf16(z2, zn);
  }
  {
    const unsigned int* p3 = (const unsigned int*)(WB + WB_P3T);
    int c = lane & 15;
    float a0 = (c < 13) ? pb3[c] : 0.f, a1 = 0.f, a2 = 0.f, a3 = 0.f;
    #pragma unroll
    for (int k2 = 0; k2 < 32; k2 += 4) {
      a0 = dot2bf(p3[(k2 + 0) * 16 + c], z2p[k2 + 0], a0);
      a1 = dot2bf(p3[(k2 + 1) * 16 + c], z2p[k2 + 1], a1);
      a2 = dot2bf(p3[(k2 + 2) * 16 + c], z2p[k2 + 2], a2);
      a3 = dot2bf(p3[(k2 + 3) * 16 + c], z2p[k2 + 3], a3);
    }
    if (lane < 13) outp[(size_t)m * 13 + lane] = (a0 + a1) + (a2 + a3);
  }
}

extern "C" void kernel_launch(void* const* d_in, const int* in_sizes, int n_in,
                              void* d_out, int out_size, void* d_ws, size_t ws_size,
                              hipStream_t stream) {
  (void)in_sizes; (void)n_in; (void)out_size; (void)ws_size;
  const float* nf   = (const float*)d_in[0];
  const int*   ei   = (const int*)d_in[1];
  const float* sw1  = (const float*)d_in[2];
  const float* sb1  = (const float*)d_in[3];
  const float* sw2  = (const float*)d_in[4];
  const float* sb2  = (const float*)d_in[5];
  const float* wih0 = (const float*)d_in[6];
  const float* whh0 = (const float*)d_in[7];
  const float* bih0 = (const float*)d_in[8];
  const float* bhh0 = (const float*)d_in[9];
  const float* wih1 = (const float*)d_in[10];
  const float* whh1 = (const float*)d_in[11];
  const float* bih1 = (const float*)d_in[12];
  const float* bhh1 = (const float*)d_in[13];
  const float* aw   = (const float*)d_in[14];
  const float* ab   = (const float*)d_in[15];
  const float* ow   = (const float*)d_in[16];
  const float* ob   = (const float*)d_in[17];
  const float* pw1  = (const float*)d_in[18];
  const float* pb1  = (const float*)d_in[19];
  const float* pw2  = (const float*)d_in[20];
  const float* pb2  = (const float*)d_in[21];
  const float* pw3  = (const float*)d_in[22];
  const float* pb3  = (const float*)d_in[23];

  char* ws = (char*)d_ws;
  float* wT = (float*)ws;                                   //   0 .. 384 KB
  unsigned short* WA = (unsigned short*)(ws + 393216);      // 384 KB (128 KB)
  unsigned short* WB = (unsigned short*)(ws + 458752);      // 448 KB (~58 KB)
  unsigned short* WE = (unsigned short*)(ws + 520192);      // ~508 KB (8 KB)
  int* rp   = (int*)(ws + 1048576);                         //   1 MB (~256 KB)
  int* col  = (int*)(ws + 1572864);                         // 1.5 MB (8 MB)
  unsigned short* henc = (unsigned short*)(ws + 10485760);  //  10 MB (32 MB)
  unsigned short* hmp  = (unsigned short*)(ws + 44040192);  //  42 MB (32 MB)
  int* bhist  = (int*)(ws + 44040192);   // 4 MB, aliases hmp (dead until k_mp)
  int* segoff = (int*)(ws + 48234496);   // 4 MB, aliases hmp (dead until k_mp)
  unsigned short* x2   = henc;           // alias: henc dead after k_mp
  float* outp = (float*)d_out;

  hipFuncSetAttribute((const void*)k_attn,
                      hipFuncAttributeMaxDynamicSharedMemorySize, SMEM_ATTN);
  k_prep<<<1, 256, 0, stream>>>(bih0, bhh0, bih1, bhh1, wT);
  k_prep_wa<<<256, 256, 0, stream>>>(wih0, whh0, wih1, whh1, WA);
  k_prep2<<<32, 256, 0, stream>>>(aw, ab, pw2, pw3, sw2, WB, WE, wT);
  k_prep3<<<32, 256, 0, stream>>>(pw1, ow, ob, pb1, WB, wT);
  k_enc<<<4096, 256, 0, stream>>>(nf, sw1, sb1, WE, sb2, henc);
  k_count<<<256, 1024, 0, stream>>>(ei, bhist);
  k_scan<<<16, 256, 0, stream>>>(bhist, rp, segoff);
  k_scatter<<<256, 1024, 0, stream>>>(ei, segoff, col);
  k_mp<<<16384, 256, 0, stream>>>(henc, rp, col, hmp);
  k_lstm<<<256, 1024, 0, stream>>>(hmp, WA, wT, x2);
  k_attn<<<2048, 512, SMEM_ATTN, stream>>>(x2, WB, wT, pb2, pb3, outp);
}

// Round 20
// 241.524 us; speedup vs baseline: 1.0617x; 1.0054x over previous
//
#include <hip/hip_runtime.h>

#define Bq 4
#define Tq 16
#define Nq 4096
#define NFq 8
#define Hq 64
#define Eq 131072
#define Cq 13
#define Mq (Bq*Nq)

typedef __attribute__((ext_vector_type(8))) short bf16x8;
typedef __attribute__((ext_vector_type(4))) float f32x4;

// ---------- helpers ----------
__device__ __forceinline__ float bf2f(unsigned short u) {
  return __uint_as_float(((unsigned int)u) << 16);
}
__device__ __forceinline__ unsigned short f2bf(float f) {
  unsigned int x = __float_as_uint(f);
  unsigned int r = x + 0x7fff + ((x >> 16) & 1);
  return (unsigned short)(r >> 16);
}
__device__ __forceinline__ float rcpf(float x) {
  float r;
  asm("v_rcp_f32 %0, %1" : "=v"(r) : "v"(x));
  return r;
}
__device__ __forceinline__ float sigf(float x) {
  return rcpf(1.f + __expf(-x));
}
__device__ __forceinline__ float tanh_c(float x) {
  float e = __expf(-2.f * x);
  return 2.f * rcpf(1.f + e) - 1.f;
}
__device__ __forceinline__ unsigned int pk_bf16(float lo, float hi) {
  unsigned int r;
  asm("v_cvt_pk_bf16_f32 %0, %1, %2" : "=v"(r) : "v"(lo), "v"(hi));
  return r;
}
__device__ __forceinline__ float dot2bf(unsigned int a, unsigned int b, float c) {
  float r;
  asm("v_dot2_f32_bf16 %0, %1, %2, %3" : "=v"(r) : "v"(a), "v"(b), "v"(c));
  return r;
}

// wT float offsets
#define O_BC0  65536
#define O_BC1  65792
#define O_QB   70144
#define O_VB   74304
#define O_B1P  95872

// WB (bf16 blob) ushort offsets (global). AQT/WVT/P1OW/P2T/P3T are k-PAIR-PACKED.
#define WB_AQT  0
#define WB_AWK  4096
#define WB_WVT  8192
#define WB_P1OW 12288
#define WB_P2T  20480
#define WB_P3T  28672
#define WB_TOT  29696

// k_attn LDS layout
#define AQT_P   0
#define WVT_P   2048
#define P1OW_P  4096
#define P2T_P   8192
#define WAVE_SCR 3648
#define SMEM_ATTN (49152 + 8 * WAVE_SCR)

// ---------- K0: LSTM bias combine ----------
__global__ __launch_bounds__(256) void k_prep(
    const float* __restrict__ bih0, const float* __restrict__ bhh0,
    const float* __restrict__ bih1, const float* __restrict__ bhh1,
    float* __restrict__ wT) {
  int i = threadIdx.x;
  wT[O_BC0 + i] = bih0[i] + bhh0[i];
  wT[O_BC1 + i] = bih1[i] + bhh1[i];
}

// ---------- K0a: pack LSTM weights into MFMA A-fragments, GATE-INTERLEAVED ----------
__global__ __launch_bounds__(256) void k_prep_wa(
    const float* __restrict__ wih0, const float* __restrict__ whh0,
    const float* __restrict__ wih1, const float* __restrict__ whh1,
    unsigned short* __restrict__ WA) {
  int i = blockIdx.x * 256 + threadIdx.x;    // 0..65535
  int j = i & 7, lane = (i >> 3) & 63, ks = (i >> 9) & 3;
  int mt = (i >> 11) & 15, L = (i >> 15) & 1;
  int rp = 16 * mt + (lane & 15);
  int orig = (rp & 3) * 64 + (rp >> 2);      // gate-major original row
  int k = 32 * ks + 8 * (lane >> 4) + j;
  const float* w = L ? (k < 64 ? wih1 : whh1) : (k < 64 ? wih0 : whh0);
  WA[i] = f2bf(w[orig * 64 + (k & 63)]);
}

// ---------- K0b: attention weight pack + encoder w2 A-frag pack ----------
__global__ __launch_bounds__(256) void k_prep2(
    const float* __restrict__ aw, const float* __restrict__ ab,
    const float* __restrict__ pw2, const float* __restrict__ pw3,
    const float* __restrict__ sw2,
    unsigned short* __restrict__ WBu, unsigned short* __restrict__ WE,
    float* __restrict__ wT) {
  int i = blockIdx.x * 256 + threadIdx.x;   // 0..8191
  if (i < 4096) {
    int k = i >> 6, ch = i & 63;
    int pidx = (k >> 1) * 128 + ch * 2 + (k & 1);
    WBu[WB_AQT + pidx] = f2bf(0.25f * aw[ch * 64 + k]);   // Aq^T, scale folded
    WBu[WB_AWK + i]    = f2bf(aw[(64 + k) * 64 + ch]);    // Wk rows (element order)
    WBu[WB_WVT + pidx] = f2bf(aw[(128 + ch) * 64 + k]);   // Wv^T
    int e = i & 7, l = (i >> 3) & 63, eks = (i >> 9) & 1, mt = i >> 10;
    WE[i] = f2bf(sw2[(mt * 16 + (l & 15)) * 64 + 32 * eks + 8 * (l >> 4) + e]);
  }
  {
    int k = i >> 6, j = i & 63;                            // P2T k<128
    int pidx = (k >> 1) * 128 + j * 2 + (k & 1);
    WBu[WB_P2T + pidx] = f2bf(pw2[j * 128 + k]);
  }
  if (i < 1024) {
    int k = i >> 4, c = i & 15;
    int pidx = (k >> 1) * 32 + c * 2 + (k & 1);
    WBu[WB_P3T + pidx] = (c < 13) ? f2bf(pw3[c * 64 + k]) : (unsigned short)0;
  }
  if (i < 64) {
    wT[O_QB + i] = 0.25f * ab[i];
    wT[O_VB + i] = ab[128 + i];
  }
}

// ---------- K0c: fold out-projection into pw1 (k-pair-packed) ----------
__global__ __launch_bounds__(256) void k_prep3(
    const float* __restrict__ pw1, const float* __restrict__ ow,
    const float* __restrict__ ob, const float* __restrict__ pb1,
    unsigned short* __restrict__ WBu, float* __restrict__ wT) {
  int i = blockIdx.x * 256 + threadIdx.x;  // 0..8191
  int j = i >> 6, k = i & 63;
  float s0 = 0.f, s1 = 0.f, s2 = 0.f, s3 = 0.f;
  for (int m2 = 0; m2 < 64; m2 += 4) {
    s0 += pw1[j * 64 + m2]     * ow[m2 * 64 + k];
    s1 += pw1[j * 64 + m2 + 1] * ow[(m2 + 1) * 64 + k];
    s2 += pw1[j * 64 + m2 + 2] * ow[(m2 + 2) * 64 + k];
    s3 += pw1[j * 64 + m2 + 3] * ow[(m2 + 3) * 64 + k];
  }
  WBu[WB_P1OW + (k >> 1) * 256 + j * 2 + (k & 1)] = f2bf((s0 + s1) + (s2 + s3));
  if (k == 0) {
    float b = pb1[j];
    for (int m2 = 0; m2 < 64; ++m2) b += pw1[j * 64 + m2] * ob[m2];
    wT[O_B1P + j] = b;
  }
}

// ---------- K1: FUSED spatial encoder (blocks 0..4095) + edge count (4096..4351) ----------
// 256 thr; LDS union: enc 19712 B, count 16384 B
__global__ __launch_bounds__(256) void k_enc_cnt(
    const float* __restrict__ nf, const float* __restrict__ w1,
    const float* __restrict__ b1, const unsigned short* __restrict__ WE,
    const float* __restrict__ b2, unsigned short* __restrict__ henc,
    const int* __restrict__ ei, int* __restrict__ bhist) {
  __shared__ __align__(16) char sm[19712];
  int tid = threadIdx.x;
  if (blockIdx.x >= 4096) {
    // ---- count: per-block LDS histogram, 32 edges/thread
    int* hist = (int*)sm;
    int cb = blockIdx.x - 4096;            // 0..255
    int t = cb & 15, seg = cb >> 4;
    #pragma unroll
    for (int i = tid; i < 4096; i += 256) hist[i] = 0;
    __syncthreads();
    const int* dstp = ei + ((t << 1) + 1) * Eq + (seg << 13);
    #pragma unroll
    for (int u = 0; u < 32; ++u) {
      int dst = dstp[(u << 8) + tid];
      atomicAdd(&hist[dst], 1);
    }
    __syncthreads();
    int* op = bhist + (cb << 12);
    #pragma unroll
    for (int i = tid; i < 4096; i += 256) op[i] = hist[i];
    return;
  }
  // ---- encoder
  float* xr = (float*)sm;                           // [64][9]
  unsigned short* H1F = (unsigned short*)(sm + 2304);  // 4096 ush
  unsigned short* OUT = (unsigned short*)(sm + 10496); // 64*72 ush
  int lane = tid & 63;
  int wv = tid >> 6;
  size_t row0 = (size_t)blockIdx.x * 64;
  {
    float2 v = ((const float2*)(nf + row0 * 8))[tid];
    int r = tid >> 2, q = tid & 3;
    xr[r * 9 + q * 2] = v.x;
    xr[r * 9 + q * 2 + 1] = v.y;
  }
  bf16x8 afr0, afr1;
  {
    const bf16x8* we8 = (const bf16x8*)WE;
    afr0 = we8[(wv * 2 + 0) * 64 + lane];
    afr1 = we8[(wv * 2 + 1) * 64 + lane];
  }
  int chb = wv * 16 + (lane >> 4) * 4;
  float4 b2v;
  b2v.x = b2[chb]; b2v.y = b2[chb + 1]; b2v.z = b2[chb + 2]; b2v.w = b2[chb + 3];
  __syncthreads();
  {
    int r = lane;
    float x0 = xr[r * 9 + 0], x1 = xr[r * 9 + 1], x2v = xr[r * 9 + 2], x3 = xr[r * 9 + 3];
    float x4 = xr[r * 9 + 4], x5 = xr[r * 9 + 5], x6 = xr[r * 9 + 6], x7 = xr[r * 9 + 7];
    #pragma unroll
    for (int run = 0; run < 2; ++run) {
      unsigned int pk4[4];
      #pragma unroll
      for (int p = 0; p < 4; ++p) {
        int j0 = wv * 16 + run * 8 + p * 2;
        const float* wr0 = w1 + j0 * 8;
        const float* wr1 = wr0 + 8;
        float a0 = b1[j0]     + wr0[0]*x0 + wr0[1]*x1 + wr0[2]*x2v + wr0[3]*x3
                              + wr0[4]*x4 + wr0[5]*x5 + wr0[6]*x6 + wr0[7]*x7;
        float a1 = b1[j0 + 1] + wr1[0]*x0 + wr1[1]*x1 + wr1[2]*x2v + wr1[3]*x3
                              + wr1[4]*x4 + wr1[5]*x5 + wr1[6]*x6 + wr1[7]*x7;
        pk4[p] = pk_bf16(fmaxf(a0, 0.f), fmaxf(a1, 0.f));
      }
      int jb = wv * 16 + run * 8;
      int ks = jb >> 5;
      int l2 = (lane & 15) | (((jb >> 3) & 3) << 4);
      int nt = lane >> 4;
      uint4 v; v.x = pk4[0]; v.y = pk4[1]; v.z = pk4[2]; v.w = pk4[3];
      *(uint4*)(&H1F[((ks * 4 + nt) * 64 + l2) * 8]) = v;
    }
  }
  __syncthreads();
  {
    #pragma unroll
    for (int nt = 0; nt < 4; ++nt) {
      f32x4 acc = (f32x4){b2v.x, b2v.y, b2v.z, b2v.w};
      bf16x8 bf0 = *(const bf16x8*)(&H1F[((0 * 4 + nt) * 64 + lane) * 8]);
      bf16x8 bf1 = *(const bf16x8*)(&H1F[((1 * 4 + nt) * 64 + lane) * 8]);
      acc = __builtin_amdgcn_mfma_f32_16x16x32_bf16(afr0, bf0, acc, 0, 0, 0);
      acc = __builtin_amdgcn_mfma_f32_16x16x32_bf16(afr1, bf1, acc, 0, 0, 0);
      int orow = nt * 16 + (lane & 15);
      uint2 pv;
      pv.x = pk_bf16(acc[0], acc[1]);
      pv.y = pk_bf16(acc[2], acc[3]);
      *(uint2*)(&OUT[orow * 72 + chb]) = pv;
    }
  }
  __syncthreads();
  {
    int rr = tid >> 2, part = tid & 3;
    uint4 v0 = *(uint4*)(&OUT[rr * 72 + part * 16]);
    uint4 v1 = *(uint4*)(&OUT[rr * 72 + part * 16 + 8]);
    *(uint4*)(henc + (row0 + rr) * 64 + part * 16) = v0;
    *(uint4*)(henc + (row0 + rr) * 64 + part * 16 + 8) = v1;
  }
}

// ---------- K3: scan -> rp + per-segment bases segoff[t*16+seg][node] ----------
__global__ __launch_bounds__(256) void k_scan(const int* __restrict__ bhist,
                                              int* __restrict__ rp,
                                              int* __restrict__ segoff) {
  int t = blockIdx.x, tid = threadIdx.x;
  __shared__ int part[256];
  int loc[16];
  int s = 0;
  #pragma unroll
  for (int j = 0; j < 16; ++j) {
    int node = tid * 16 + j;
    int v = 0;
    #pragma unroll
    for (int seg = 0; seg < 16; ++seg)
      v += bhist[((t + (seg << 4)) << 12) + node];
    loc[j] = v;
    s += v;
  }
  part[tid] = s;
  __syncthreads();
  if (tid == 0) {
    int run = 0;
    for (int i2 = 0; i2 < 256; ++i2) { int v = part[i2]; part[i2] = run; run += v; }
  }
  __syncthreads();
  int off = part[tid];
  #pragma unroll
  for (int j = 0; j < 16; ++j) {
    int node = tid * 16 + j;
    rp[t * (Nq + 1) + node] = off;
    int running = off;
    #pragma unroll
    for (int seg = 0; seg < 16; ++seg) {
      segoff[(((t << 4) + seg) << 12) + node] = running;
      running += bhist[((t + (seg << 4)) << 12) + node];
    }
    off += loc[j];
  }
  if (tid == 255) rp[t * (Nq + 1) + Nq] = off;
}

// ---------- K4: scatter via LDS positions (no global atomics) ----------
__global__ __launch_bounds__(1024) void k_scatter(const int* __restrict__ ei,
    const int* __restrict__ segoff, int* __restrict__ col) {
  __shared__ int loff[4096];
  int b = blockIdx.x;                      // 256
  int t = b & 15, seg = b >> 4;
  int tid = threadIdx.x;
  for (int i = tid; i < 4096; i += 1024)
    loff[i] = segoff[(((t << 4) + seg) << 12) + i];
  __syncthreads();
  const int* srcp = ei + (t << 1) * Eq + (seg << 13);
  const int* dstp = ei + ((t << 1) + 1) * Eq + (seg << 13);
  #pragma unroll
  for (int u = 0; u < 8; ++u) {
    int e = (u << 10) + tid;
    int src = srcp[e];
    int dst = dstp[e];
    int pos = atomicAdd(&loff[dst], 1);
    col[(t << 17) + pos] = src;
  }
}

// ---------- K5: message passing; t PHASE-PARTITIONED per XCD (1 slab live) ----------
__global__ __launch_bounds__(256) void k_mp(const unsigned short* __restrict__ henc,
    const int* __restrict__ rp, const int* __restrict__ col,
    unsigned short* __restrict__ hmp) {
  int lane = threadIdx.x & 63;
  int bkk = blockIdx.x;                    // 16384
  int t = (bkk & 7) | ((bkk >> 13) << 3);
  int n = ((bkk >> 3) & 1023) * 4 + __builtin_amdgcn_readfirstlane(threadIdx.x >> 6);
  const int* rpt = rp + t * (Nq + 1);
  const int* colt = col + (t << 17);
  int e0 = rpt[n], e1 = rpt[n + 1];
  int half = lane >> 5;
  int b2 = (lane >> 3) & 3;
  int c8 = (lane & 7) << 3;
  const unsigned short* hb2 = henc + (size_t)b2 * 4194304 + t * 262144 + c8;
  float acc[8] = {0.f, 0.f, 0.f, 0.f, 0.f, 0.f, 0.f, 0.f};
  int e = e0;
  for (; e + 8 <= e1; e += 8) {
    int i0 = colt[e + half];
    int i1 = colt[e + 2 + half];
    int i2 = colt[e + 4 + half];
    int i3 = colt[e + 6 + half];
    uint4 p0 = *(const uint4*)(hb2 + i0 * 64);
    uint4 p1 = *(const uint4*)(hb2 + i1 * 64);
    uint4 p2 = *(const uint4*)(hb2 + i2 * 64);
    uint4 p3 = *(const uint4*)(hb2 + i3 * 64);
    acc[0] += bf2f((unsigned short)(p0.x & 0xffff)) + bf2f((unsigned short)(p1.x & 0xffff))
            + bf2f((unsigned short)(p2.x & 0xffff)) + bf2f((unsigned short)(p3.x & 0xffff));
    acc[1] += bf2f((unsigned short)(p0.x >> 16)) + bf2f((unsigned short)(p1.x >> 16))
            + bf2f((unsigned short)(p2.x >> 16)) + bf2f((unsigned short)(p3.x >> 16));
    acc[2] += bf2f((unsigned short)(p0.y & 0xffff)) + bf2f((unsigned short)(p1.y & 0xffff))
            + bf2f((unsigned short)(p2.y & 0xffff)) + bf2f((unsigned short)(p3.y & 0xffff));
    acc[3] += bf2f((unsigned short)(p0.y >> 16)) + bf2f((unsigned short)(p1.y >> 16))
            + bf2f((unsigned short)(p2.y >> 16)) + bf2f((unsigned short)(p3.y >> 16));
    acc[4] += bf2f((unsigned short)(p0.z & 0xffff)) + bf2f((unsigned short)(p1.z & 0xffff))
            + bf2f((unsigned short)(p2.z & 0xffff)) + bf2f((unsigned short)(p3.z & 0xffff));
    acc[5] += bf2f((unsigned short)(p0.z >> 16)) + bf2f((unsigned short)(p1.z >> 16))
            + bf2f((unsigned short)(p2.z >> 16)) + bf2f((unsigned short)(p3.z >> 16));
    acc[6] += bf2f((unsigned short)(p0.w & 0xffff)) + bf2f((unsigned short)(p1.w & 0xffff))
            + bf2f((unsigned short)(p2.w & 0xffff)) + bf2f((unsigned short)(p3.w & 0xffff));
    acc[7] += bf2f((unsigned short)(p0.w >> 16)) + bf2f((unsigned short)(p1.w >> 16))
            + bf2f((unsigned short)(p2.w >> 16)) + bf2f((unsigned short)(p3.w >> 16));
  }
  if (half == 0) {
    for (; e < e1; ++e) {
      int i0 = colt[e];
      uint4 p0 = *(const uint4*)(hb2 + i0 * 64);
      acc[0] += bf2f((unsigned short)(p0.x & 0xffff));
      acc[1] += bf2f((unsigned short)(p0.x >> 16));
      acc[2] += bf2f((unsigned short)(p0.y & 0xffff));
      acc[3] += bf2f((unsigned short)(p0.y >> 16));
      acc[4] += bf2f((unsigned short)(p0.z & 0xffff));
      acc[5] += bf2f((unsigned short)(p0.z >> 16));
      acc[6] += bf2f((unsigned short)(p0.w & 0xffff));
      acc[7] += bf2f((unsigned short)(p0.w >> 16));
    }
  }
  #pragma unroll
  for (int i = 0; i < 8; ++i) acc[i] += __shfl_xor(acc[i], 32);
  uint4 ps = *(const uint4*)(hb2 + n * 64);
  int deg = e1 - e0;
  if (half == 0) {
    uint4 out;
    if (deg > 0) {
      float sc = 0.5f * rcpf((float)deg);
      float s0 = bf2f((unsigned short)(ps.x & 0xffff)) * 0.5f + acc[0] * sc;
      float s1 = bf2f((unsigned short)(ps.x >> 16))    * 0.5f + acc[1] * sc;
      float s2 = bf2f((unsigned short)(ps.y & 0xffff)) * 0.5f + acc[2] * sc;
      float s3 = bf2f((unsigned short)(ps.y >> 16))    * 0.5f + acc[3] * sc;
      float s4 = bf2f((unsigned short)(ps.z & 0xffff)) * 0.5f + acc[4] * sc;
      float s5 = bf2f((unsigned short)(ps.z >> 16))    * 0.5f + acc[5] * sc;
      float s6 = bf2f((unsigned short)(ps.w & 0xffff)) * 0.5f + acc[6] * sc;
      float s7 = bf2f((unsigned short)(ps.w >> 16))    * 0.5f + acc[7] * sc;
      out.x = pk_bf16(s0, s1);
      out.y = pk_bf16(s2, s3);
      out.z = pk_bf16(s4, s5);
      out.w = pk_bf16(s6, s7);
    } else {
      out = ps;
    }
    *(uint4*)(hmp + (size_t)b2 * 4194304 + t * 262144 + n * 64 + c8) = out;
  }
}

// ---------- K6: fused 2-layer LSTM; 64 seqs/block, 2-barrier pipelined steps ----------
__global__ __launch_bounds__(1024) void k_lstm(
    const unsigned short* __restrict__ hmp,
    const unsigned short* __restrict__ WA,
    const float* __restrict__ wT,
    unsigned short* __restrict__ x2) {
  __shared__ unsigned short XF[2][4096];
  __shared__ unsigned short H0F[2][4096];
  __shared__ unsigned short H1F[2][4096];
  __shared__ unsigned short OUTB[64 * 68];
  int tid = threadIdx.x;
  int l = tid & 63;
  int w = tid >> 6;
  int mtp = w >> 1, ntp = w & 1;
  int m0 = blockIdx.x << 6;

  bf16x8 afr[2][2][4];
  const bf16x8* wa8 = (const bf16x8*)WA;
  #pragma unroll
  for (int L = 0; L < 2; ++L)
    #pragma unroll
    for (int mt2 = 0; mt2 < 2; ++mt2)
      #pragma unroll
      for (int ks = 0; ks < 4; ++ks)
        afr[L][mt2][ks] = wa8[((L * 16 + (2 * mtp + mt2)) * 4 + ks) * 64 + l];

  float4 bias0[2], bias1[2];
  int hbase[2], obase[2];
  #pragma unroll
  for (int mt2 = 0; mt2 < 2; ++mt2) {
    int ch = 4 * (2 * mtp + mt2) + (l >> 4);
    bias0[mt2].x = wT[O_BC0 + ch];       bias0[mt2].y = wT[O_BC0 + 64 + ch];
    bias0[mt2].z = wT[O_BC0 + 128 + ch]; bias0[mt2].w = wT[O_BC0 + 192 + ch];
    bias1[mt2].x = wT[O_BC1 + ch];       bias1[mt2].y = wT[O_BC1 + 64 + ch];
    bias1[mt2].z = wT[O_BC1 + 128 + ch]; bias1[mt2].w = wT[O_BC1 + 192 + ch];
    int l2 = (l & 15) | (((ch >> 3) & 3) << 4);
    hbase[mt2] = (ch >> 5) * 2048 + l2 * 8 + (ch & 7);
    obase[mt2] = (l & 15) * 68 + ch;
  }
  float c0a[2][2] = {{0.f, 0.f}, {0.f, 0.f}};
  float c1a[2][2] = {{0.f, 0.f}, {0.f, 0.f}};

  int sA = tid >> 4, c4 = (tid & 15) << 2;
  int xfidx = (((c4 >> 5) * 4 + (sA >> 4)) * 64 + ((sA & 15) | (((c4 >> 3) & 3) << 4))) * 8 + (c4 & 7);
  int mm = m0 + sA;
  int bb = mm >> 12, nn = mm & 4095;
  const unsigned short* srcb = hmp + ((size_t)(bb * 16) * 4096 + (size_t)nn) * 64 + c4;
  unsigned short* x2g = x2 + (size_t)mm * (Tq * Hq) + c4;
  int outsrc = sA * 68 + c4;

  int* hz0 = (int*)&H0F[1][0];
  int* hz1 = (int*)&H1F[1][0];
  for (int i = tid; i < 2048; i += 1024) { hz0[i] = 0; hz1[i] = 0; }

  uint2 xv = *(const uint2*)srcb;
  *(uint2*)(&XF[0][0] + xfidx) = xv;
  __syncthreads();

  for (int t = 0; t < Tq; ++t) {
    int cur = t & 1, prv = cur ^ 1;

    if (t > 0) {
      uint2 ov = *(const uint2*)(OUTB + outsrc);
      *(uint2*)(x2g + (t - 1) * 64) = ov;
    }
    if (t < Tq - 1) xv = *(const uint2*)(srcb + (t + 1) * 262144);
    {
      f32x4 acc[2][2];
      #pragma unroll
      for (int mt2 = 0; mt2 < 2; ++mt2)
        #pragma unroll
        for (int nt2 = 0; nt2 < 2; ++nt2) {
          float4 bv = bias0[mt2];
          acc[mt2][nt2] = (f32x4){bv.x, bv.y, bv.z, bv.w};
        }
      #pragma unroll
      for (int nt2 = 0; nt2 < 2; ++nt2) {
        int nt = 2 * ntp + nt2;
        #pragma unroll
        for (int ks = 0; ks < 4; ++ks) {
          const unsigned short* bs = (ks < 2) ? &XF[cur][0] : &H0F[prv][0];
          bf16x8 bf = *(const bf16x8*)(bs + (((ks & 1) * 4 + nt) * 64 + l) * 8);
          acc[0][nt2] = __builtin_amdgcn_mfma_f32_16x16x32_bf16(afr[0][0][ks], bf, acc[0][nt2], 0, 0, 0);
          acc[1][nt2] = __builtin_amdgcn_mfma_f32_16x16x32_bf16(afr[0][1][ks], bf, acc[1][nt2], 0, 0, 0);
        }
      }
      #pragma unroll
      for (int mt2 = 0; mt2 < 2; ++mt2) {
        float hh[2];
        #pragma unroll
        for (int nt2 = 0; nt2 < 2; ++nt2) {
          f32x4 g = acc[mt2][nt2];
          float ig = sigf(g[0]);
          float fg = sigf(g[1]);
          float gg = tanh_c(g[2]);
          float og = sigf(g[3]);
          float c = fg * c0a[mt2][nt2] + ig * gg;
          c0a[mt2][nt2] = c;
          hh[nt2] = og * tanh_c(c);
        }
        unsigned int pk = pk_bf16(hh[0], hh[1]);
        int base = hbase[mt2] + 2 * ntp * 512;
        H0F[cur][base]       = (unsigned short)pk;
        H0F[cur][base + 512] = (unsigned short)(pk >> 16);
      }
    }
    __syncthreads();

    {
      f32x4 acc[2][2];
      #pragma unroll
      for (int mt2 = 0; mt2 < 2; ++mt2)
        #pragma unroll
        for (int nt2 = 0; nt2 < 2; ++nt2) {
          float4 bv = bias1[mt2];
          acc[mt2][nt2] = (f32x4){bv.x, bv.y, bv.z, bv.w};
        }
      #pragma unroll
      for (int nt2 = 0; nt2 < 2; ++nt2) {
        int nt = 2 * ntp + nt2;
        #pragma unroll
        for (int ks = 0; ks < 4; ++ks) {
          const unsigned short* bs = (ks < 2) ? &H0F[cur][0] : &H1F[prv][0];
          bf16x8 bf = *(const bf16x8*)(bs + (((ks & 1) * 4 + nt) * 64 + l) * 8);
          acc[0][nt2] = __builtin_amdgcn_mfma_f32_16x16x32_bf16(afr[1][0][ks], bf, acc[0][nt2], 0, 0, 0);
          acc[1][nt2] = __builtin_amdgcn_mfma_f32_16x16x32_bf16(afr[1][1][ks], bf, acc[1][nt2], 0, 0, 0);
        }
      }
      #pragma unroll
      for (int mt2 = 0; mt2 < 2; ++mt2) {
        float hh[2];
        #pragma unroll
        for (int nt2 = 0; nt2 < 2; ++nt2) {
          f32x4 g = acc[mt2][nt2];
          float ig = sigf(g[0]);
          float fg = sigf(g[1]);
          float gg = tanh_c(g[2]);
          float og = sigf(g[3]);
          float c = fg * c1a[mt2][nt2] + ig * gg;
          c1a[mt2][nt2] = c;
          hh[nt2] = og * tanh_c(c);
        }
        unsigned int pk = pk_bf16(hh[0], hh[1]);
        int base = hbase[mt2] + 2 * ntp * 512;
        H1F[cur][base]       = (unsigned short)pk;
        H1F[cur][base + 512] = (unsigned short)(pk >> 16);
        int ob = obase[mt2] + 2 * ntp * 1088;
        OUTB[ob]        = (unsigned short)pk;
        OUTB[ob + 1088] = (unsigned short)(pk >> 16);
      }
    }
    if (t < Tq - 1) *(uint2*)(&XF[prv][0] + xfidx) = xv;
    __syncthreads();
  }
  {
    uint2 ov = *(const uint2*)(OUTB + outsrc);
    *(uint2*)(x2g + (Tq - 1) * 64) = ov;
  }
}

// ---------- K7: attention + MLP; dot2_f32_bf16 GEMVs, packed weights ----------
__global__ __launch_bounds__(512, 4) void k_attn(const unsigned short* __restrict__ x2,
    const unsigned short* __restrict__ WB, const float* __restrict__ wp,
    const float* __restrict__ pb2, const float* __restrict__ pb3,
    float* __restrict__ outp) {
  extern __shared__ char smem[];
  unsigned int* WLu = (unsigned int*)smem;
  int tid = threadIdx.x;
  int lane = tid & 63;
  int wid = tid >> 6;
  {
    const uint4* src = (const uint4*)WB;
    uint4* dstw = (uint4*)smem;
    for (int i = tid; i < 3072; i += 512)
      dstw[i] = src[(i < 512) ? i : i + 512];
  }
  char* wbase = smem + 49152 + wid * WAVE_SCR;
  unsigned short* xw = (unsigned short*)wbase;
  float* q = (float*)(wbase + 2304);
  unsigned int* op = (unsigned int*)(wbase + 2304);
  unsigned int* qkp = (unsigned int*)(wbase + 2560);
  unsigned int* hbp = qkp;
  float* pz = (float*)(wbase + 3104);
  unsigned int* z2p = (unsigned int*)(wbase + 3104);
  unsigned int* z1p = (unsigned int*)(wbase + 3360);
  int m = (blockIdx.x << 3) + wid;
  {
    const uint4* xp = (const uint4*)(x2 + (size_t)m * 1024);
    #pragma unroll
    for (int u = 0; u < 2; ++u) {
      uint4 pv = xp[lane * 2 + u];
      int f0 = (lane * 2 + u) * 8;
      int t = f0 >> 6, ch0 = f0 & 63;
      *(uint4*)(xw + t * 72 + ch0) = pv;
    }
  }
  __syncthreads();
  {
    const unsigned short* xr = xw + 15 * 72;
    float a0 = wp[O_QB + lane], a1 = 0.f, a2 = 0.f, a3 = 0.f;
    #pragma unroll
    for (int k2 = 0; k2 < 32; k2 += 4) {
      a0 = dot2bf(WLu[AQT_P + (k2 + 0) * 64 + lane], *(const unsigned int*)(xr + 2 * (k2 + 0)), a0);
      a1 = dot2bf(WLu[AQT_P + (k2 + 1) * 64 + lane], *(const unsigned int*)(xr + 2 * (k2 + 1)), a1);
      a2 = dot2bf(WLu[AQT_P + (k2 + 2) * 64 + lane], *(const unsigned int*)(xr + 2 * (k2 + 2)), a2);
      a3 = dot2bf(WLu[AQT_P + (k2 + 3) * 64 + lane], *(const unsigned int*)(xr + 2 * (k2 + 3)), a3);
    }
    q[lane] = (a0 + a1) + (a2 + a3);
  }
  #pragma unroll
  for (int h = 0; h < 4; ++h) {
    float a0 = 0.f, a1 = 0.f, a2 = 0.f, a3 = 0.f;
    #pragma unroll
    for (int d = 0; d < 16; d += 4) {
      a0 += bf2f(WB[WB_AWK + (h * 16 + d + 0) * 64 + lane]) * q[h * 16 + d + 0];
      a1 += bf2f(WB[WB_AWK + (h * 16 + d + 1) * 64 + lane]) * q[h * 16 + d + 1];
      a2 += bf2f(WB[WB_AWK + (h * 16 + d + 2) * 64 + lane]) * q[h * 16 + d + 2];
      a3 += bf2f(WB[WB_AWK + (h * 16 + d + 3) * 64 + lane]) * q[h * 16 + d + 3];
    }
    float a = (a0 + a1) + (a2 + a3);
    float an = __shfl_xor(a, 1);
    if (!(lane & 1)) qkp[h * 33 + (lane >> 1)] = pk_bf16(a, an);
  }
  {
    int hh = lane >> 4, tt = lane & 15;
    const unsigned short* xr = xw + tt * 72;
    float a0 = 0.f, a1 = 0.f, a2 = 0.f, a3 = 0.f;
    #pragma unroll
    for (int c2 = 0; c2 < 32; c2 += 4) {
      a0 = dot2bf(qkp[hh * 33 + c2 + 0], *(const unsigned int*)(xr + 2 * (c2 + 0)), a0);
      a1 = dot2bf(qkp[hh * 33 + c2 + 1], *(const unsigned int*)(xr + 2 * (c2 + 1)), a1);
      a2 = dot2bf(qkp[hh * 33 + c2 + 2], *(const unsigned int*)(xr + 2 * (c2 + 2)), a2);
      a3 = dot2bf(qkp[hh * 33 + c2 + 3], *(const unsigned int*)(xr + 2 * (c2 + 3)), a3);
    }
    float sc = (a0 + a1) + (a2 + a3);
    float mx = sc;
    mx = fmaxf(mx, __shfl_xor(mx, 1));
    mx = fmaxf(mx, __shfl_xor(mx, 2));
    mx = fmaxf(mx, __shfl_xor(mx, 4));
    mx = fmaxf(mx, __shfl_xor(mx, 8));
    float e = __expf(sc - mx);
    float sum = e;
    sum += __shfl_xor(sum, 1);
    sum += __shfl_xor(sum, 2);
    sum += __shfl_xor(sum, 4);
    sum += __shfl_xor(sum, 8);
    pz[lane] = e * rcpf(sum);
  }
  {
    float hb0 = 0.f, hb1 = 0.f, hb2 = 0.f, hb3 = 0.f;
    #pragma unroll
    for (int t = 0; t < 16; ++t) {
      float xv = bf2f(xw[t * 72 + lane]);
      hb0 += pz[t] * xv;
      hb1 += pz[16 + t] * xv;
      hb2 += pz[32 + t] * xv;
      hb3 += pz[48 + t] * xv;
    }
    float n0 = __shfl_xor(hb0, 1);
    float n1 = __shfl_xor(hb1, 1);
    float n2 = __shfl_xor(hb2, 1);
    float n3 = __shfl_xor(hb3, 1);
    if (!(lane & 1)) {
      int p = lane >> 1;
      hbp[p]          = pk_bf16(hb0, n0);
      hbp[33 + p]     = pk_bf16(hb1, n1);
      hbp[66 + p]     = pk_bf16(hb2, n2);
      hbp[99 + p]     = pk_bf16(hb3, n3);
    }
  }
  {
    int hsel = lane >> 4;
    float a0 = wp[O_VB + lane], a1 = 0.f, a2 = 0.f, a3 = 0.f;
    #pragma unroll
    for (int k2 = 0; k2 < 32; k2 += 4) {
      a0 = dot2bf(WLu[WVT_P + (k2 + 0) * 64 + lane], hbp[hsel * 33 + k2 + 0], a0);
      a1 = dot2bf(WLu[WVT_P + (k2 + 1) * 64 + lane], hbp[hsel * 33 + k2 + 1], a1);
      a2 = dot2bf(WLu[WVT_P + (k2 + 2) * 64 + lane], hbp[hsel * 33 + k2 + 2], a2);
      a3 = dot2bf(WLu[WVT_P + (k2 + 3) * 64 + lane], hbp[hsel * 33 + k2 + 3], a3);
    }
    float o = (a0 + a1) + (a2 + a3);
    float on = __shfl_xor(o, 1);
    if (!(lane & 1)) op[lane >> 1] = pk_bf16(o, on);
  }
  {
    float a0 = wp[O_B1P + lane], a1 = 0.f;
    float b0 = wp[O_B1P + 64 + lane], b1 = 0.f;
    #pragma unroll
    for (int k2 = 0; k2 < 32; k2 += 2) {
      unsigned int ov0 = op[k2], ov1 = op[k2 + 1];
      a0 = dot2bf(WLu[P1OW_P + (k2 + 0) * 128 + lane], ov0, a0);
      a1 = dot2bf(WLu[P1OW_P + (k2 + 1) * 128 + lane], ov1, a1);
      b0 = dot2bf(WLu[P1OW_P + (k2 + 0) * 128 + 64 + lane], ov0, b0);
      b1 = dot2bf(WLu[P1OW_P + (k2 + 1) * 128 + 64 + lane], ov1, b1);
    }
    float ra = fmaxf(a0 + a1, 0.f);
    float rb = fmaxf(b0 + b1, 0.f);
    float ran = __shfl_xor(ra, 1);
    float rbn = __shfl_xor(rb, 1);
    if (!(lane & 1)) {
      z1p[lane >> 1]      = pk_bf16(ra, ran);
      z1p[32 + (lane >> 1)] = pk_bf16(rb, rbn);
    }
  }
  {
    float a0 = pb2[lane], a1 = 0.f, a2 = 0.f, a3 = 0.f;
    #pragma unroll
    for (int k2 = 0; k2 < 64; k2 += 4) {
      a0 = dot2bf(WLu[P2T_P + (k2 + 0) * 64 + lane], z1p[k2 + 0], a0);
      a1 = dot2bf(WLu[P2T_P + (k2 + 1) * 64 + lane], z1p[k2 + 1], a1);
      a2 = dot2bf(WLu[P2T_P + (k2 + 2) * 64 + lane], z1p[k2 + 2], a2);
      a3 = dot2bf(WLu[P2T_P + (k2 + 3) * 64 + lane], z1p[k2 + 3], a3);
    }
    float z2 = fmaxf((a0 + a1) + (a2 + a3), 0.f);
    float zn = __shfl_xor(z2, 1);
    if (!(lane & 1)) z2p[lane >> 1] = pk_bf16(z2, zn);
  }
  {
    const unsigned int* p3 = (const unsigned int*)(WB + WB_P3T);
    int c = lane & 15;
    float a0 = (c < 13) ? pb3[c] : 0.f, a1 = 0.f, a2 = 0.f, a3 = 0.f;
    #pragma unroll
    for (int k2 = 0; k2 < 32; k2 += 4) {
      a0 = dot2bf(p3[(k2 + 0) * 16 + c], z2p[k2 + 0], a0);
      a1 = dot2bf(p3[(k2 + 1) * 16 + c], z2p[k2 + 1], a1);
      a2 = dot2bf(p3[(k2 + 2) * 16 + c], z2p[k2 + 2], a2);
      a3 = dot2bf(p3[(k2 + 3) * 16 + c], z2p[k2 + 3], a3);
    }
    if (lane < 13) outp[(size_t)m * 13 + lane] = (a0 + a1) + (a2 + a3);
  }
}

extern "C" void kernel_launch(void* const* d_in, const int* in_sizes, int n_in,
                              void* d_out, int out_size, void* d_ws, size_t ws_size,
                              hipStream_t stream) {
  (void)in_sizes; (void)n_in; (void)out_size; (void)ws_size;
  const float* nf   = (const float*)d_in[0];
  const int*   ei   = (const int*)d_in[1];
  const float* sw1  = (const float*)d_in[2];
  const float* sb1  = (const float*)d_in[3];
  const float* sw2  = (const float*)d_in[4];
  const float* sb2  = (const float*)d_in[5];
  const float* wih0 = (const float*)d_in[6];
  const float* whh0 = (const float*)d_in[7];
  const float* bih0 = (const float*)d_in[8];
  const float* bhh0 = (const float*)d_in[9];
  const float* wih1 = (const float*)d_in[10];
  const float* whh1 = (const float*)d_in[11];
  const float* bih1 = (const float*)d_in[12];
  const float* bhh1 = (const float*)d_in[13];
  const float* aw   = (const float*)d_in[14];
  const float* ab   = (const float*)d_in[15];
  const float* ow   = (const float*)d_in[16];
  const float* ob   = (const float*)d_in[17];
  const float* pw1  = (const float*)d_in[18];
  const float* pb1  = (const float*)d_in[19];
  const float* pw2  = (const float*)d_in[20];
  const float* pb2  = (const float*)d_in[21];
  const float* pw3  = (const float*)d_in[22];
  const float* pb3  = (const float*)d_in[23];

  char* ws = (char*)d_ws;
  float* wT = (float*)ws;                                   //   0 .. 384 KB
  unsigned short* WA = (unsigned short*)(ws + 393216);      // 384 KB (128 KB)
  unsigned short* WB = (unsigned short*)(ws + 458752);      // 448 KB (~58 KB)
  unsigned short* WE = (unsigned short*)(ws + 520192);      // ~508 KB (8 KB)
  int* rp   = (int*)(ws + 1048576);                         //   1 MB (~256 KB)
  int* col  = (int*)(ws + 1572864);                         // 1.5 MB (8 MB)
  unsigned short* henc = (unsigned short*)(ws + 10485760);  //  10 MB (32 MB)
  unsigned short* hmp  = (unsigned short*)(ws + 44040192);  //  42 MB (32 MB)
  int* bhist  = (int*)(ws + 44040192);   // 4 MB, aliases hmp (dead until k_mp)
  int* segoff = (int*)(ws + 48234496);   // 4 MB, aliases hmp (dead until k_mp)
  unsigned short* x2   = henc;           // alias: henc dead after k_mp
  float* outp = (float*)d_out;

  hipFuncSetAttribute((const void*)k_attn,
                      hipFuncAttributeMaxDynamicSharedMemorySize, SMEM_ATTN);
  k_prep<<<1, 256, 0, stream>>>(bih0, bhh0, bih1, bhh1, wT);
  k_prep_wa<<<256, 256, 0, stream>>>(wih0, whh0, wih1, whh1, WA);
  k_prep2<<<32, 256, 0, stream>>>(aw, ab, pw2, pw3, sw2, WB, WE, wT);
  k_prep3<<<32, 256, 0, stream>>>(pw1, ow, ob, pb1, WB, wT);
  k_enc_cnt<<<4352, 256, 0, stream>>>(nf, sw1, sb1, WE, sb2, henc, ei, bhist);
  k_scan<<<16, 256, 0, stream>>>(bhist, rp, segoff);
  k_scatter<<<256, 1024, 0, stream>>>(ei, segoff, col);
  k_mp<<<16384, 256, 0, stream>>>(henc, rp, col, hmp);
  k_lstm<<<256, 1024, 0, stream>>>(hmp, WA, wT, x2);
  k_attn<<<2048, 512, SMEM_ATTN, stream>>>(x2, WB, wT, pb2, pb3, outp);
}